// Round 3
// baseline (1066.375 us; speedup 1.0000x reference)
//
#include <hip/hip_runtime.h>
#include <math.h>

// Problem constants (B=4, T=2048, C=448, H=8, d=56)
#define NB 4
#define NT 2048
#define NC 448
#define NH 8
#define ND 56
#define NM (NB * NT)          // 8192 rows
#define SCALE 0.04724555912615705f  // 1/sqrt(448)

// ---------------------------------------------------------------------------
// Kernel 1: QKV projection.  y = x @ W for W in {Wq, Wk, Wv} (blockIdx.z),
// output written head-split: dst[((b*H + h)*T + t)*D + c].
// Tile 64x64, BK=32, 256 threads, 4x4 micro-tile, fp32.
// ---------------------------------------------------------------------------
__global__ __launch_bounds__(256) void qkv_gemm_kernel(
    const float* __restrict__ x,
    const float* __restrict__ Wq, const float* __restrict__ Wk,
    const float* __restrict__ Wv,
    float* __restrict__ qo, float* __restrict__ ko, float* __restrict__ vo)
{
    const int z = blockIdx.z;
    const float* __restrict__ W   = (z == 0) ? Wq : ((z == 1) ? Wk : Wv);
    float* __restrict__       dst = (z == 0) ? qo : ((z == 1) ? ko : vo);

    const int tid = threadIdx.x;
    const int tx = tid & 15;        // 0..15 (cols)
    const int ty = tid >> 4;        // 0..15 (rows)
    const int rowBase = blockIdx.y * 64;
    const int colBase = blockIdx.x * 64;

    __shared__ float As[64][36];    // pad 32->36: float4-writable, 2-way reads
    __shared__ float Bs[32][64];

    float acc[4][4] = {};

    for (int k0 = 0; k0 < NC; k0 += 32) {
        // Stage A tile (64 rows x 32 k): two float4 per thread.
        {
            const int r  = tid >> 2;            // 0..63
            const int kg = (tid & 3) * 8;       // 0,8,16,24
            const float4 a0 = *reinterpret_cast<const float4*>(
                &x[(size_t)(rowBase + r) * NC + k0 + kg]);
            const float4 a1 = *reinterpret_cast<const float4*>(
                &x[(size_t)(rowBase + r) * NC + k0 + kg + 4]);
            *reinterpret_cast<float4*>(&As[r][kg])     = a0;
            *reinterpret_cast<float4*>(&As[r][kg + 4]) = a1;
        }
        // Stage B tile (32 k x 64 n): two float4 per thread.
        {
            const int kr = tid >> 4;            // 0..15
            const int ng = (tid & 15) * 4;      // 0..60
            const float4 b0 = *reinterpret_cast<const float4*>(
                &W[(size_t)(k0 + kr) * NC + colBase + ng]);
            const float4 b1 = *reinterpret_cast<const float4*>(
                &W[(size_t)(k0 + kr + 16) * NC + colBase + ng]);
            *reinterpret_cast<float4*>(&Bs[kr][ng])      = b0;
            *reinterpret_cast<float4*>(&Bs[kr + 16][ng]) = b1;
        }
        __syncthreads();
        #pragma unroll
        for (int kk = 0; kk < 32; ++kk) {
            const float a0 = As[ty * 4 + 0][kk];
            const float a1 = As[ty * 4 + 1][kk];
            const float a2 = As[ty * 4 + 2][kk];
            const float a3 = As[ty * 4 + 3][kk];
            const float4 b = *reinterpret_cast<const float4*>(&Bs[kk][tx * 4]);
            acc[0][0] += a0 * b.x; acc[0][1] += a0 * b.y; acc[0][2] += a0 * b.z; acc[0][3] += a0 * b.w;
            acc[1][0] += a1 * b.x; acc[1][1] += a1 * b.y; acc[1][2] += a1 * b.z; acc[1][3] += a1 * b.w;
            acc[2][0] += a2 * b.x; acc[2][1] += a2 * b.y; acc[2][2] += a2 * b.z; acc[2][3] += a2 * b.w;
            acc[3][0] += a3 * b.x; acc[3][1] += a3 * b.y; acc[3][2] += a3 * b.z; acc[3][3] += a3 * b.w;
        }
        __syncthreads();
    }

    // Epilogue: scatter into head-split layout [B][H][T][D].
    #pragma unroll
    for (int i = 0; i < 4; ++i) {
        const int m = rowBase + ty * 4 + i;
        const int b = m >> 11;          // /T (2048)
        const int t = m & (NT - 1);
        #pragma unroll
        for (int j = 0; j < 4; ++j) {
            const int n = colBase + tx * 4 + j;
            const int h = n / ND;
            const int c = n - h * ND;
            dst[(((size_t)b * NH + h) * NT + t) * ND + c] = acc[i][j];
        }
    }
}

// ---------------------------------------------------------------------------
// Kernel 2: causal flash attention (fp32).
// Grid: (T/64, B*H). Block 256 threads.
// Thread t: q-row r = t>>2 of the 64-row Q tile, sub = t&3 owns dims
// [sub*14, sub*14+13] of the output and keys j = 4*jj + sub in score phase.
// Longest q-tiles (largest qb) are launched first for load balance.
// ---------------------------------------------------------------------------
__global__ __launch_bounds__(256) void attn_kernel(
    const float* __restrict__ q, const float* __restrict__ k,
    const float* __restrict__ v, float* __restrict__ att)
{
    const int qb = (gridDim.x - 1 - blockIdx.x) * 64;   // reversed: big tiles first
    const int bh = blockIdx.y;                 // b*H + h
    const int b  = bh >> 3;
    const int h  = bh & 7;

    const float* __restrict__ Q = q + (size_t)bh * NT * ND;
    const float* __restrict__ K = k + (size_t)bh * NT * ND;
    const float* __restrict__ V = v + (size_t)bh * NT * ND;

    const int tid  = threadIdx.x;
    const int r    = tid >> 2;                 // 0..63
    const int sub  = tid & 3;                  // 0..3
    const int cbase = sub * 14;

    __shared__ float Ks[64][ND];               // 14336 B
    __shared__ float Vs[64][ND];               // 14336 B
    __shared__ float Ps[64][68];               // padded: 17408 B

    // Q row into registers (4 lanes per row redundantly; L1/L2 absorbs it).
    float4 qreg[14];
    {
        const float4* Qg = reinterpret_cast<const float4*>(Q + (size_t)(qb + r) * ND);
        #pragma unroll
        for (int c4 = 0; c4 < 14; ++c4) qreg[c4] = Qg[c4];
    }

    float2 acc2[7];
    #pragma unroll
    for (int i = 0; i < 7; ++i) acc2[i] = make_float2(0.f, 0.f);
    float m_r = -INFINITY;
    float l_r = 0.f;

    for (int kb = 0; kb <= qb; kb += 64) {
        __syncthreads();   // protect Ks/Vs from previous iteration's readers
        {
            const float4* Kg = reinterpret_cast<const float4*>(K + (size_t)kb * ND);
            const float4* Vg = reinterpret_cast<const float4*>(V + (size_t)kb * ND);
            float4* Ksf = reinterpret_cast<float4*>(&Ks[0][0]);
            float4* Vsf = reinterpret_cast<float4*>(&Vs[0][0]);
            for (int i = tid; i < 64 * ND / 4; i += 256) {
                Ksf[i] = Kg[i];
                Vsf[i] = Vg[i];
            }
        }
        __syncthreads();

        // ---- scores: 16 keys per thread (j = 4*jj + sub) ----
        float s[16];
        #pragma unroll
        for (int jj = 0; jj < 16; ++jj) {
            const int j = jj * 4 + sub;
            const float4* kr = reinterpret_cast<const float4*>(&Ks[j][0]);
            float dot = 0.f;
            #pragma unroll
            for (int c4 = 0; c4 < 14; ++c4) {
                const float4 kv = kr[c4];
                dot += qreg[c4].x * kv.x + qreg[c4].y * kv.y +
                       qreg[c4].z * kv.z + qreg[c4].w * kv.w;
            }
            s[jj] = dot * SCALE;
        }
        if (kb == qb) {   // diagonal tile: mask keys j > r
            #pragma unroll
            for (int jj = 0; jj < 16; ++jj)
                if (jj * 4 + sub > r) s[jj] = -1e30f;
        }

        // ---- online softmax update (4-lane group reduce) ----
        float tmax = s[0];
        #pragma unroll
        for (int jj = 1; jj < 16; ++jj) tmax = fmaxf(tmax, s[jj]);
        tmax = fmaxf(tmax, __shfl_xor(tmax, 1));
        tmax = fmaxf(tmax, __shfl_xor(tmax, 2));
        const float mnew  = fmaxf(m_r, tmax);
        const float alpha = __expf(m_r - mnew);   // exp(-inf)=0 on first tile
        float tsum = 0.f;
        #pragma unroll
        for (int jj = 0; jj < 16; ++jj) {
            const float p = __expf(s[jj] - mnew);
            s[jj] = p;
            tsum += p;
        }
        tsum += __shfl_xor(tsum, 1);
        tsum += __shfl_xor(tsum, 2);
        l_r = l_r * alpha + tsum;
        m_r = mnew;
        #pragma unroll
        for (int i = 0; i < 7; ++i) { acc2[i].x *= alpha; acc2[i].y *= alpha; }

        // publish P (row r written only by its own 4-lane group -> wave-local)
        #pragma unroll
        for (int jj = 0; jj < 16; ++jj) Ps[r][jj * 4 + sub] = s[jj];

        // ---- PV accumulate: acc += P[r][:] @ V[:, cbase..cbase+13] ----
        const float* pr = &Ps[r][0];
        #pragma unroll 4
        for (int j4 = 0; j4 < 16; ++j4) {
            const float4 p4 = *reinterpret_cast<const float4*>(pr + j4 * 4);
            #pragma unroll
            for (int e = 0; e < 4; ++e) {
                const int j = j4 * 4 + e;
                const float p = (e == 0) ? p4.x : (e == 1) ? p4.y : (e == 2) ? p4.z : p4.w;
                const float2* vr = reinterpret_cast<const float2*>(&Vs[j][cbase]);
                #pragma unroll
                for (int c2 = 0; c2 < 7; ++c2) {
                    const float2 vv = vr[c2];
                    acc2[c2].x += p * vv.x;
                    acc2[c2].y += p * vv.y;
                }
            }
        }
    }

    // normalize + write to [B, T, C] layout for the output projection
    const float inv = 1.0f / l_r;
    float* orow = att + ((size_t)(b * NT + qb + r)) * NC + h * ND + cbase;
    #pragma unroll
    for (int c2 = 0; c2 < 7; ++c2) {
        float2 o;
        o.x = acc2[c2].x * inv;
        o.y = acc2[c2].y * inv;
        *reinterpret_cast<float2*>(orow + c2 * 2) = o;
    }
}

// ---------------------------------------------------------------------------
// Kernel 3: output projection.  out = att @ Wp + bp.  Same tiling as kernel 1.
// ---------------------------------------------------------------------------
__global__ __launch_bounds__(256) void proj_gemm_kernel(
    const float* __restrict__ A, const float* __restrict__ W,
    const float* __restrict__ bias, float* __restrict__ out)
{
    const int tid = threadIdx.x;
    const int tx = tid & 15;
    const int ty = tid >> 4;
    const int rowBase = blockIdx.y * 64;
    const int colBase = blockIdx.x * 64;

    __shared__ float As[64][36];
    __shared__ float Bs[32][64];

    float acc[4][4] = {};

    for (int k0 = 0; k0 < NC; k0 += 32) {
        {
            const int r  = tid >> 2;
            const int kg = (tid & 3) * 8;
            const float4 a0 = *reinterpret_cast<const float4*>(
                &A[(size_t)(rowBase + r) * NC + k0 + kg]);
            const float4 a1 = *reinterpret_cast<const float4*>(
                &A[(size_t)(rowBase + r) * NC + k0 + kg + 4]);
            *reinterpret_cast<float4*>(&As[r][kg])     = a0;
            *reinterpret_cast<float4*>(&As[r][kg + 4]) = a1;
        }
        {
            const int kr = tid >> 4;
            const int ng = (tid & 15) * 4;
            const float4 b0 = *reinterpret_cast<const float4*>(
                &W[(size_t)(k0 + kr) * NC + colBase + ng]);
            const float4 b1 = *reinterpret_cast<const float4*>(
                &W[(size_t)(k0 + kr + 16) * NC + colBase + ng]);
            *reinterpret_cast<float4*>(&Bs[kr][ng])      = b0;
            *reinterpret_cast<float4*>(&Bs[kr + 16][ng]) = b1;
        }
        __syncthreads();
        #pragma unroll
        for (int kk = 0; kk < 32; ++kk) {
            const float a0 = As[ty * 4 + 0][kk];
            const float a1 = As[ty * 4 + 1][kk];
            const float a2 = As[ty * 4 + 2][kk];
            const float a3 = As[ty * 4 + 3][kk];
            const float4 b = *reinterpret_cast<const float4*>(&Bs[kk][tx * 4]);
            acc[0][0] += a0 * b.x; acc[0][1] += a0 * b.y; acc[0][2] += a0 * b.z; acc[0][3] += a0 * b.w;
            acc[1][0] += a1 * b.x; acc[1][1] += a1 * b.y; acc[1][2] += a1 * b.z; acc[1][3] += a1 * b.w;
            acc[2][0] += a2 * b.x; acc[2][1] += a2 * b.y; acc[2][2] += a2 * b.z; acc[2][3] += a2 * b.w;
            acc[3][0] += a3 * b.x; acc[3][1] += a3 * b.y; acc[3][2] += a3 * b.z; acc[3][3] += a3 * b.w;
        }
        __syncthreads();
    }

    const float4 bv = *reinterpret_cast<const float4*>(&bias[colBase + tx * 4]);
    #pragma unroll
    for (int i = 0; i < 4; ++i) {
        const int m = rowBase + ty * 4 + i;
        float4 o;
        o.x = acc[i][0] + bv.x;
        o.y = acc[i][1] + bv.y;
        o.z = acc[i][2] + bv.z;
        o.w = acc[i][3] + bv.w;
        *reinterpret_cast<float4*>(&out[(size_t)m * NC + colBase + tx * 4]) = o;
    }
}

// ---------------------------------------------------------------------------
extern "C" void kernel_launch(void* const* d_in, const int* in_sizes, int n_in,
                              void* d_out, int out_size, void* d_ws, size_t ws_size,
                              hipStream_t stream)
{
    const float* x  = (const float*)d_in[0];
    const float* Wq = (const float*)d_in[1];
    const float* Wk = (const float*)d_in[2];
    const float* Wv = (const float*)d_in[3];
    const float* Wp = (const float*)d_in[4];
    const float* bp = (const float*)d_in[5];
    float* out = (float*)d_out;

    const size_t BTC = (size_t)NM * NC;        // 3,670,016 floats
    float* qw  = (float*)d_ws;
    float* kw  = qw + BTC;
    float* vw  = kw + BTC;
    float* aw  = vw + BTC;                     // attention output [B,T,C]

    dim3 blk(256);
    // QKV projections: grid (Ntiles=7, Mtiles=128, 3 weights)
    qkv_gemm_kernel<<<dim3(NC / 64, NM / 64, 3), blk, 0, stream>>>(
        x, Wq, Wk, Wv, qw, kw, vw);
    // Attention: grid (T/64 q-tiles, B*H)
    attn_kernel<<<dim3(NT / 64, NB * NH), blk, 0, stream>>>(qw, kw, vw, aw);
    // Output projection
    proj_gemm_kernel<<<dim3(NC / 64, NM / 64, 1), blk, 0, stream>>>(
        aw, Wp, bp, out);
}

// Round 4
// 429.469 us; speedup vs baseline: 2.4830x; 2.4830x over previous
//
#include <hip/hip_runtime.h>
#include <math.h>

// Problem constants (B=4, T=2048, C=448, H=8, d=56)
#define NB 4
#define NT 2048
#define NC 448
#define NH 8
#define ND 56
#define NM (NB * NT)          // 8192 rows
#define SCALE 0.04724555912615705f  // 1/sqrt(448)

typedef __attribute__((ext_vector_type(8))) short bf16x8;
typedef __attribute__((ext_vector_type(4))) float f32x4;

__device__ __forceinline__ unsigned short f2bf(float f) {
    unsigned u = __float_as_uint(f);
    u += 0x7fffu + ((u >> 16) & 1u);       // round-to-nearest-even
    return (unsigned short)(u >> 16);
}

// ---------------------------------------------------------------------------
// Kernel 1: QKV projection (fp32 compute).  y = x @ W for W in {Wq,Wk,Wv}.
// Outputs bf16:  q,k -> [BH][T][56] row-major;  v -> TRANSPOSED [BH][56][T].
// Tile 64x64, BK=32, 256 threads, 4x4 micro-tile.
// ---------------------------------------------------------------------------
__global__ __launch_bounds__(256) void qkv_gemm_kernel(
    const float* __restrict__ x,
    const float* __restrict__ Wq, const float* __restrict__ Wk,
    const float* __restrict__ Wv,
    unsigned short* __restrict__ qo, unsigned short* __restrict__ ko,
    unsigned short* __restrict__ vo)
{
    const int z = blockIdx.z;
    const float* __restrict__ W = (z == 0) ? Wq : ((z == 1) ? Wk : Wv);

    const int tid = threadIdx.x;
    const int tx = tid & 15;        // 0..15 (cols)
    const int ty = tid >> 4;        // 0..15 (rows)
    const int rowBase = blockIdx.y * 64;
    const int colBase = blockIdx.x * 64;

    __shared__ float As[64][36];    // pad 32->36: float4-writable, 2-way reads
    __shared__ float Bs[32][64];

    float acc[4][4] = {};

    for (int k0 = 0; k0 < NC; k0 += 32) {
        {
            const int r  = tid >> 2;            // 0..63
            const int kg = (tid & 3) * 8;       // 0,8,16,24
            const float4 a0 = *reinterpret_cast<const float4*>(
                &x[(size_t)(rowBase + r) * NC + k0 + kg]);
            const float4 a1 = *reinterpret_cast<const float4*>(
                &x[(size_t)(rowBase + r) * NC + k0 + kg + 4]);
            *reinterpret_cast<float4*>(&As[r][kg])     = a0;
            *reinterpret_cast<float4*>(&As[r][kg + 4]) = a1;
        }
        {
            const int kr = tid >> 4;            // 0..15
            const int ng = (tid & 15) * 4;      // 0..60
            const float4 b0 = *reinterpret_cast<const float4*>(
                &W[(size_t)(k0 + kr) * NC + colBase + ng]);
            const float4 b1 = *reinterpret_cast<const float4*>(
                &W[(size_t)(k0 + kr + 16) * NC + colBase + ng]);
            *reinterpret_cast<float4*>(&Bs[kr][ng])      = b0;
            *reinterpret_cast<float4*>(&Bs[kr + 16][ng]) = b1;
        }
        __syncthreads();
        #pragma unroll
        for (int kk = 0; kk < 32; ++kk) {
            const float a0 = As[ty * 4 + 0][kk];
            const float a1 = As[ty * 4 + 1][kk];
            const float a2 = As[ty * 4 + 2][kk];
            const float a3 = As[ty * 4 + 3][kk];
            const float4 b = *reinterpret_cast<const float4*>(&Bs[kk][tx * 4]);
            acc[0][0] += a0 * b.x; acc[0][1] += a0 * b.y; acc[0][2] += a0 * b.z; acc[0][3] += a0 * b.w;
            acc[1][0] += a1 * b.x; acc[1][1] += a1 * b.y; acc[1][2] += a1 * b.z; acc[1][3] += a1 * b.w;
            acc[2][0] += a2 * b.x; acc[2][1] += a2 * b.y; acc[2][2] += a2 * b.z; acc[2][3] += a2 * b.w;
            acc[3][0] += a3 * b.x; acc[3][1] += a3 * b.y; acc[3][2] += a3 * b.z; acc[3][3] += a3 * b.w;
        }
        __syncthreads();
    }

    // Epilogue: bf16 convert + layout-specific pack.
    // A 4-aligned group of 4 output cols never crosses a head boundary
    // (56 % 4 == 0), so the j-quad lies in one head with consecutive c.
    const int n0 = colBase + tx * 4;
    const int h  = n0 / ND;
    const int c0 = n0 - h * ND;
    const int tb = rowBase + ty * 4;
    const int b  = tb >> 11;             // / NT
    const int t0 = tb & (NT - 1);
    const int bh = b * NH + h;

    if (z < 2) {
        unsigned short* __restrict__ dst16 = (z == 0) ? qo : ko;
        #pragma unroll
        for (int i = 0; i < 4; ++i) {
            ushort4 pk;
            pk.x = f2bf(acc[i][0]); pk.y = f2bf(acc[i][1]);
            pk.z = f2bf(acc[i][2]); pk.w = f2bf(acc[i][3]);
            *reinterpret_cast<ushort4*>(
                dst16 + ((size_t)bh * NT + (t0 + i)) * ND + c0) = pk;
        }
    } else {
        // v transposed: vo[bh][c][t], pack 4 consecutive t per write
        #pragma unroll
        for (int j = 0; j < 4; ++j) {
            ushort4 pk;
            pk.x = f2bf(acc[0][j]); pk.y = f2bf(acc[1][j]);
            pk.z = f2bf(acc[2][j]); pk.w = f2bf(acc[3][j]);
            *reinterpret_cast<ushort4*>(
                vo + ((size_t)bh * ND + (c0 + j)) * NT + t0) = pk;
        }
    }
}

// ---------------------------------------------------------------------------
// Kernel 2: causal flash attention, bf16 MFMA (16x16x32), fp32 softmax.
// Grid (T/64, B*H), 256 threads = 4 waves; wave w owns q-rows [16w,16w+15].
// KV tile = 64. K tile LDS [64 key][64 d] (d padded, zeros), Vt LDS
// [64 d][64 key] -- both XOR-swizzled per 16B slot: phys = row*8 + (u^(row&7)).
// MFMA layouts (m89-verified): D col=lane&15, row=(lane>>4)*4+reg;
// A row=lane&15, k=8*(lane>>4)+j; B col=lane&15, same k grouping.
// ---------------------------------------------------------------------------
__global__ __launch_bounds__(256) void attn_mfma_kernel(
    const unsigned short* __restrict__ q, const unsigned short* __restrict__ k,
    const unsigned short* __restrict__ vt, float* __restrict__ att)
{
    const int qb = (gridDim.x - 1 - blockIdx.x) * 64;   // big tiles first
    const int bh = blockIdx.y;
    const int b  = bh >> 3;
    const int h  = bh & 7;

    const int tid = threadIdx.x;
    const int w   = tid >> 6;       // wave 0..3
    const int l   = tid & 63;
    const int lg  = l >> 4;         // 0..3
    const int lr  = l & 15;         // 0..15

    __shared__ unsigned short Ks [64 * 64];    // 8 KiB
    __shared__ unsigned short Vts[64 * 64];    // 8 KiB
    __shared__ unsigned short Pl[4][16 * 64];  // 8 KiB (per-wave P)

    const unsigned short* __restrict__ Qg = q  + (size_t)bh * NT * ND;
    const unsigned short* __restrict__ Kg = k  + (size_t)bh * NT * ND;
    const unsigned short* __restrict__ Vg = vt + (size_t)bh * ND * NT;

    // Q fragments (A-operand), held across the whole kv loop.
    bf16x8 qf[2];
    {
        const int row = qb + w * 16 + lr;
        #pragma unroll
        for (int hh = 0; hh < 2; ++hh) {
            const int d0 = hh * 32 + lg * 8;
            bf16x8 tmp = {0, 0, 0, 0, 0, 0, 0, 0};
            if (d0 < ND)
                tmp = *reinterpret_cast<const bf16x8*>(Qg + (size_t)row * ND + d0);
            qf[hh] = tmp;
        }
    }

    const f32x4 fzero = {0.f, 0.f, 0.f, 0.f};
    f32x4 o[4];
    #pragma unroll
    for (int n = 0; n < 4; ++n) o[n] = fzero;
    float mrun[4] = {-INFINITY, -INFINITY, -INFINITY, -INFINITY};
    float lrun[4] = {0.f, 0.f, 0.f, 0.f};

    for (int kb = 0; kb <= qb; kb += 64) {
        __syncthreads();   // protect LDS from previous iteration's readers
        // ---- stage K and Vt tiles (swizzled); d>=56 rows/slots zeroed ----
        #pragma unroll
        for (int cc = 0; cc < 2; ++cc) {
            const int ch  = tid + cc * 256;      // 0..511
            const int row = ch >> 3;             // 0..63
            const int u   = ch & 7;              // 16B slot
            uint4 kv = make_uint4(0u, 0u, 0u, 0u);
            uint4 vv = make_uint4(0u, 0u, 0u, 0u);
            if (u < 7)   // d slots 0..6 cover d 0..55 exactly
                kv = *reinterpret_cast<const uint4*>(
                    Kg + (size_t)(kb + row) * ND + u * 8);
            if (row < ND)
                vv = *reinterpret_cast<const uint4*>(
                    Vg + (size_t)row * NT + kb + u * 8);
            *reinterpret_cast<uint4*>(Ks  + (row * 8 + (u ^ (row & 7))) * 8) = kv;
            *reinterpret_cast<uint4*>(Vts + (row * 8 + (u ^ (row & 7))) * 8) = vv;
        }
        __syncthreads();

        // ---- QK^T: S[16 q][64 key] per wave (8 MFMAs) ----
        f32x4 s[4];
        #pragma unroll
        for (int n = 0; n < 4; ++n) {
            const int krow = n * 16 + lr;
            const bf16x8 kf0 = *reinterpret_cast<const bf16x8*>(
                Ks + (krow * 8 + ((0 + lg) ^ (krow & 7))) * 8);
            const bf16x8 kf1 = *reinterpret_cast<const bf16x8*>(
                Ks + (krow * 8 + ((4 + lg) ^ (krow & 7))) * 8);
            f32x4 acc = fzero;
            acc = __builtin_amdgcn_mfma_f32_16x16x32_bf16(qf[0], kf0, acc, 0, 0, 0);
            acc = __builtin_amdgcn_mfma_f32_16x16x32_bf16(qf[1], kf1, acc, 0, 0, 0);
            s[n] = acc;
        }

        // scale, then causal mask on the diagonal tile
        #pragma unroll
        for (int n = 0; n < 4; ++n) {
            #pragma unroll
            for (int r = 0; r < 4; ++r) s[n][r] *= SCALE;
        }
        if (kb == qb) {
            #pragma unroll
            for (int n = 0; n < 4; ++n) {
                const int key = n * 16 + lr;            // local key index
                #pragma unroll
                for (int r = 0; r < 4; ++r) {
                    const int qr = w * 16 + lg * 4 + r; // local q index
                    if (key > qr) s[n][r] = -1e30f;
                }
            }
        }

        // ---- online softmax (rows live in 16-lane groups: shfl 1,2,4,8) ----
        float alpha[4];
        #pragma unroll
        for (int r = 0; r < 4; ++r) {
            float tmax = fmaxf(fmaxf(s[0][r], s[1][r]), fmaxf(s[2][r], s[3][r]));
            tmax = fmaxf(tmax, __shfl_xor(tmax, 1));
            tmax = fmaxf(tmax, __shfl_xor(tmax, 2));
            tmax = fmaxf(tmax, __shfl_xor(tmax, 4));
            tmax = fmaxf(tmax, __shfl_xor(tmax, 8));
            const float mnew = fmaxf(mrun[r], tmax);
            alpha[r] = __expf(mrun[r] - mnew);   // first tile: exp(-inf)=0
            mrun[r]  = mnew;
            float tsum = 0.f;
            #pragma unroll
            for (int n = 0; n < 4; ++n) {
                const float p = __expf(s[n][r] - mnew);
                s[n][r] = p;
                tsum += p;
            }
            tsum += __shfl_xor(tsum, 1);
            tsum += __shfl_xor(tsum, 2);
            tsum += __shfl_xor(tsum, 4);
            tsum += __shfl_xor(tsum, 8);
            lrun[r] = lrun[r] * alpha[r] + tsum;
        }
        #pragma unroll
        for (int n = 0; n < 4; ++n) {
            #pragma unroll
            for (int r = 0; r < 4; ++r) o[n][r] *= alpha[r];
        }

        // ---- P -> bf16 -> per-wave swizzled LDS, read back as A-frags ----
        unsigned short* Pw = Pl[w];
        #pragma unroll
        for (int n = 0; n < 4; ++n) {
            const int u = n * 2 + (lr >> 3);
            #pragma unroll
            for (int r = 0; r < 4; ++r) {
                const int prow = lg * 4 + r;
                Pw[(prow * 8 + (u ^ (prow & 7))) * 8 + (lr & 7)] = f2bf(s[n][r]);
            }
        }
        const bf16x8 pf0 = *reinterpret_cast<const bf16x8*>(
            Pw + (lr * 8 + ((0 + lg) ^ (lr & 7))) * 8);
        const bf16x8 pf1 = *reinterpret_cast<const bf16x8*>(
            Pw + (lr * 8 + ((4 + lg) ^ (lr & 7))) * 8);

        // ---- PV: O[16 q][64 d] += P @ V  (8 MFMAs) ----
        #pragma unroll
        for (int n = 0; n < 4; ++n) {
            const int vrow = n * 16 + lr;
            const bf16x8 vf0 = *reinterpret_cast<const bf16x8*>(
                Vts + (vrow * 8 + ((0 + lg) ^ (vrow & 7))) * 8);
            const bf16x8 vf1 = *reinterpret_cast<const bf16x8*>(
                Vts + (vrow * 8 + ((4 + lg) ^ (vrow & 7))) * 8);
            o[n] = __builtin_amdgcn_mfma_f32_16x16x32_bf16(pf0, vf0, o[n], 0, 0, 0);
            o[n] = __builtin_amdgcn_mfma_f32_16x16x32_bf16(pf1, vf1, o[n], 0, 0, 0);
        }
    }

    // ---- epilogue: normalize, write fp32 [B][T][C] for output projection ----
    #pragma unroll
    for (int r = 0; r < 4; ++r) {
        const float inv = 1.0f / lrun[r];
        const int trow = qb + w * 16 + lg * 4 + r;
        float* __restrict__ orow = att + ((size_t)b * NT + trow) * NC + h * ND;
        #pragma unroll
        for (int n = 0; n < 4; ++n) {
            const int c = n * 16 + lr;
            if (c < ND) orow[c] = o[n][r] * inv;
        }
    }
}

// ---------------------------------------------------------------------------
// Kernel 3: output projection (fp32).  out = att @ Wp + bp.
// ---------------------------------------------------------------------------
__global__ __launch_bounds__(256) void proj_gemm_kernel(
    const float* __restrict__ A, const float* __restrict__ W,
    const float* __restrict__ bias, float* __restrict__ out)
{
    const int tid = threadIdx.x;
    const int tx = tid & 15;
    const int ty = tid >> 4;
    const int rowBase = blockIdx.y * 64;
    const int colBase = blockIdx.x * 64;

    __shared__ float As[64][36];
    __shared__ float Bs[32][64];

    float acc[4][4] = {};

    for (int k0 = 0; k0 < NC; k0 += 32) {
        {
            const int r  = tid >> 2;
            const int kg = (tid & 3) * 8;
            const float4 a0 = *reinterpret_cast<const float4*>(
                &A[(size_t)(rowBase + r) * NC + k0 + kg]);
            const float4 a1 = *reinterpret_cast<const float4*>(
                &A[(size_t)(rowBase + r) * NC + k0 + kg + 4]);
            *reinterpret_cast<float4*>(&As[r][kg])     = a0;
            *reinterpret_cast<float4*>(&As[r][kg + 4]) = a1;
        }
        {
            const int kr = tid >> 4;
            const int ng = (tid & 15) * 4;
            const float4 b0 = *reinterpret_cast<const float4*>(
                &W[(size_t)(k0 + kr) * NC + colBase + ng]);
            const float4 b1 = *reinterpret_cast<const float4*>(
                &W[(size_t)(k0 + kr + 16) * NC + colBase + ng]);
            *reinterpret_cast<float4*>(&Bs[kr][ng])      = b0;
            *reinterpret_cast<float4*>(&Bs[kr + 16][ng]) = b1;
        }
        __syncthreads();
        #pragma unroll
        for (int kk = 0; kk < 32; ++kk) {
            const float a0 = As[ty * 4 + 0][kk];
            const float a1 = As[ty * 4 + 1][kk];
            const float a2 = As[ty * 4 + 2][kk];
            const float a3 = As[ty * 4 + 3][kk];
            const float4 b = *reinterpret_cast<const float4*>(&Bs[kk][tx * 4]);
            acc[0][0] += a0 * b.x; acc[0][1] += a0 * b.y; acc[0][2] += a0 * b.z; acc[0][3] += a0 * b.w;
            acc[1][0] += a1 * b.x; acc[1][1] += a1 * b.y; acc[1][2] += a1 * b.z; acc[1][3] += a1 * b.w;
            acc[2][0] += a2 * b.x; acc[2][1] += a2 * b.y; acc[2][2] += a2 * b.z; acc[2][3] += a2 * b.w;
            acc[3][0] += a3 * b.x; acc[3][1] += a3 * b.y; acc[3][2] += a3 * b.z; acc[3][3] += a3 * b.w;
        }
        __syncthreads();
    }

    const float4 bv = *reinterpret_cast<const float4*>(&bias[colBase + tx * 4]);
    #pragma unroll
    for (int i = 0; i < 4; ++i) {
        const int m = rowBase + ty * 4 + i;
        float4 o;
        o.x = acc[i][0] + bv.x;
        o.y = acc[i][1] + bv.y;
        o.z = acc[i][2] + bv.z;
        o.w = acc[i][3] + bv.w;
        *reinterpret_cast<float4*>(&out[(size_t)m * NC + colBase + tx * 4]) = o;
    }
}

// ---------------------------------------------------------------------------
extern "C" void kernel_launch(void* const* d_in, const int* in_sizes, int n_in,
                              void* d_out, int out_size, void* d_ws, size_t ws_size,
                              hipStream_t stream)
{
    const float* x  = (const float*)d_in[0];
    const float* Wq = (const float*)d_in[1];
    const float* Wk = (const float*)d_in[2];
    const float* Wv = (const float*)d_in[3];
    const float* Wp = (const float*)d_in[4];
    const float* bp = (const float*)d_in[5];
    float* out = (float*)d_out;

    const size_t NQKV = (size_t)NB * NH * NT * ND;     // 3,670,016 bf16 each
    unsigned short* qw  = (unsigned short*)d_ws;
    unsigned short* kw  = qw + NQKV;
    unsigned short* vtw = kw + NQKV;                   // transposed [BH][56][T]
    float* aw = (float*)(vtw + NQKV);                  // fp32 [B][T][C]

    dim3 blk(256);
    qkv_gemm_kernel<<<dim3(NC / 64, NM / 64, 3), blk, 0, stream>>>(
        x, Wq, Wk, Wv, qw, kw, vtw);
    attn_mfma_kernel<<<dim3(NT / 64, NB * NH), blk, 0, stream>>>(
        qw, kw, vtw, aw);
    proj_gemm_kernel<<<dim3(NC / 64, NM / 64, 1), blk, 0, stream>>>(
        aw, Wp, bp, out);
}

// Round 8
// 303.261 us; speedup vs baseline: 3.5164x; 1.4162x over previous
//
#include <hip/hip_runtime.h>
#include <math.h>

// Problem constants (B=4, T=2048, C=448, H=8, d=56)
#define NB 4
#define NT 2048
#define NC 448
#define NH 8
#define ND 56
#define NM (NB * NT)          // 8192 rows
#define SCALE 0.04724555912615705f  // 1/sqrt(448)

typedef __attribute__((ext_vector_type(8))) short bf16x8;
typedef __attribute__((ext_vector_type(4))) float f32x4;

__device__ __forceinline__ unsigned short f2bf(float f) {
    unsigned u = __float_as_uint(f);
    u += 0x7fffu + ((u >> 16) & 1u);       // round-to-nearest-even
    return (unsigned short)(u >> 16);
}
__device__ __forceinline__ float bf2f(unsigned short h) {
    return __uint_as_float(((unsigned)h) << 16);
}

// async global->LDS, 16B per lane; lds dest must be wave-uniform base
__device__ __forceinline__ void gl_lds16(const unsigned short* g, unsigned short* l) {
    __builtin_amdgcn_global_load_lds(
        (const __attribute__((address_space(1))) unsigned int*)g,
        (__attribute__((address_space(3))) unsigned int*)l,
        16, 0, 0);
}

// swizzled 16B-slot index inside a [rows][32-bf16] tile (4 slots/row)
__device__ __forceinline__ int sw_slot(int row, int u) {
    return row * 4 + (u ^ ((row >> 1) & 3));
}

// ---------------------------------------------------------------------------
// Kernel 0a: x (fp32 [8192][448]) -> xh, xl (bf16 hi/lo, same layout)
// ---------------------------------------------------------------------------
__global__ __launch_bounds__(256) void conv_x_kernel(
    const float* __restrict__ x, unsigned short* __restrict__ xh,
    unsigned short* __restrict__ xl)
{
    const size_t i4 = ((size_t)blockIdx.x * 256 + threadIdx.x) * 4;
    const float4 v = *reinterpret_cast<const float4*>(x + i4);
    ushort4 h, l;
    h.x = f2bf(v.x); l.x = f2bf(v.x - bf2f(h.x));
    h.y = f2bf(v.y); l.y = f2bf(v.y - bf2f(h.y));
    h.z = f2bf(v.z); l.z = f2bf(v.z - bf2f(h.z));
    h.w = f2bf(v.w); l.w = f2bf(v.w - bf2f(h.w));
    *reinterpret_cast<ushort4*>(xh + i4) = h;
    *reinterpret_cast<ushort4*>(xl + i4) = l;
}

// ---------------------------------------------------------------------------
// Kernel 0b: W (fp32 [K=448][N=448]) -> Wt hi/lo (bf16 [N][K], transposed).
// z selects {Wq, Wk, Wv, Wp}. 32x32 LDS tile transpose, block 256 (32x8).
// ---------------------------------------------------------------------------
__global__ __launch_bounds__(256) void conv_wt_kernel(
    const float* __restrict__ Wq, const float* __restrict__ Wk,
    const float* __restrict__ Wv, const float* __restrict__ Wp,
    unsigned short* __restrict__ wth, unsigned short* __restrict__ wtl)
{
    const int z = blockIdx.z;
    const float* __restrict__ W =
        (z == 0) ? Wq : ((z == 1) ? Wk : ((z == 2) ? Wv : Wp));
    unsigned short* __restrict__ oh = wth + (size_t)z * NC * NC;
    unsigned short* __restrict__ ol = wtl + (size_t)z * NC * NC;

    __shared__ float t[32][33];
    const int tx = threadIdx.x & 31;
    const int ty = threadIdx.x >> 5;         // 0..7
    const int x0 = blockIdx.x * 32;          // n base (src cols)
    const int y0 = blockIdx.y * 32;          // k base (src rows)

    #pragma unroll
    for (int i = 0; i < 4; ++i)
        t[ty + i * 8][tx] = W[(size_t)(y0 + ty + i * 8) * NC + x0 + tx];
    __syncthreads();
    #pragma unroll
    for (int i = 0; i < 4; ++i) {
        const int n = x0 + ty + i * 8;
        const int k = y0 + tx;
        const float v = t[tx][ty + i * 8];
        const unsigned short h = f2bf(v);
        oh[(size_t)n * NC + k] = h;
        ol[(size_t)n * NC + k] = f2bf(v - bf2f(h));
    }
}

// ---------------------------------------------------------------------------
// Kernel 1: QKV projection via split-bf16 MFMA (ah*bh + ah*bl + al*bh).
// A = x hi/lo [M][448] row-major, B = Wt hi/lo [N][448] (transposed).
// Tile 128x64, BK=32, 256 thr = 4 waves (2x2), wave tile 64x32.
// Staging: global_load_lds w16, linear LDS dest + inverse-swizzled global
// source; fragment reads use sw_slot (rule #21 both-sides pattern).
// Outputs bf16: q,k -> [BH][T][56]; v -> transposed [BH][56][T].
// ---------------------------------------------------------------------------
__global__ __launch_bounds__(256) void qkv_mfma_kernel(
    const unsigned short* __restrict__ xh, const unsigned short* __restrict__ xl,
    const unsigned short* __restrict__ wth, const unsigned short* __restrict__ wtl,
    unsigned short* __restrict__ qo, unsigned short* __restrict__ ko,
    unsigned short* __restrict__ vo)
{
    const int z = blockIdx.z;
    const unsigned short* __restrict__ BTH = wth + (size_t)z * NC * NC;
    const unsigned short* __restrict__ BTL = wtl + (size_t)z * NC * NC;

    __shared__ unsigned short Ah[128 * 32], Al[128 * 32];
    __shared__ unsigned short Bh[64 * 32],  Bl[64 * 32];
    const int tid = threadIdx.x;
    const int l  = tid & 63, w = tid >> 6;
    const int lg = l >> 4,  lr = l & 15;
    const int wr = w >> 1,  wc = w & 1;
    const int rowBase = blockIdx.y * 128;
    const int colBase = blockIdx.x * 64;

    f32x4 acc[4][2];
    #pragma unroll
    for (int m = 0; m < 4; ++m)
        #pragma unroll
        for (int n = 0; n < 2; ++n) acc[m][n] = (f32x4){0.f, 0.f, 0.f, 0.f};

    for (int k0 = 0; k0 < NC; k0 += 32) {
        __syncthreads();
        #pragma unroll
        for (int i = 0; i < 2; ++i) {
            const int p   = w * 64 + 256 * i + l;
            const int row = p >> 2, ps = p & 3;
            const int u   = ps ^ ((row >> 1) & 3);
            const size_t src = (size_t)(rowBase + row) * NC + k0 + u * 8;
            const int dst = (w * 64 + 256 * i) * 8;     // ush elems, wave-uniform
            gl_lds16(xh + src, Ah + dst);
            gl_lds16(xl + src, Al + dst);
        }
        {
            const int p   = w * 64 + l;
            const int row = p >> 2, ps = p & 3;
            const int u   = ps ^ ((row >> 1) & 3);
            const size_t src = (size_t)(colBase + row) * NC + k0 + u * 8;
            gl_lds16(BTH + src, Bh + w * 512);
            gl_lds16(BTL + src, Bl + w * 512);
        }
        __syncthreads();

        bf16x8 a_h[4], a_l[4], b_h[2], b_l[2];
        #pragma unroll
        for (int m = 0; m < 4; ++m) {
            const int row = wr * 64 + m * 16 + lr;
            const int s   = sw_slot(row, lg) * 8;
            a_h[m] = *reinterpret_cast<const bf16x8*>(Ah + s);
            a_l[m] = *reinterpret_cast<const bf16x8*>(Al + s);
        }
        #pragma unroll
        for (int n = 0; n < 2; ++n) {
            const int row = wc * 32 + n * 16 + lr;
            const int s   = sw_slot(row, lg) * 8;
            b_h[n] = *reinterpret_cast<const bf16x8*>(Bh + s);
            b_l[n] = *reinterpret_cast<const bf16x8*>(Bl + s);
        }
        #pragma unroll
        for (int m = 0; m < 4; ++m)
            #pragma unroll
            for (int n = 0; n < 2; ++n) {
                acc[m][n] = __builtin_amdgcn_mfma_f32_16x16x32_bf16(
                    a_h[m], b_h[n], acc[m][n], 0, 0, 0);
                acc[m][n] = __builtin_amdgcn_mfma_f32_16x16x32_bf16(
                    a_h[m], b_l[n], acc[m][n], 0, 0, 0);
                acc[m][n] = __builtin_amdgcn_mfma_f32_16x16x32_bf16(
                    a_l[m], b_h[n], acc[m][n], 0, 0, 0);
            }
    }

    // Epilogue: D row=(lg*4+reg), col=lr within each 16x16 frag (m89 layout).
    const int mW = rowBase + wr * 64;
    const int nW = colBase + wc * 32;
    if (z < 2) {
        unsigned short* __restrict__ dst = (z == 0) ? qo : ko;
        #pragma unroll
        for (int m = 0; m < 4; ++m) {
            #pragma unroll
            for (int n = 0; n < 2; ++n) {
                const int gcol = nW + n * 16 + lr;
                const int h = gcol / ND, c = gcol - h * ND;
                #pragma unroll
                for (int r = 0; r < 4; ++r) {
                    const int grow = mW + m * 16 + lg * 4 + r;
                    const int b = grow >> 11, t = grow & (NT - 1);
                    dst[((size_t)(b * NH + h) * NT + t) * ND + c] =
                        f2bf(acc[m][n][r]);
                }
            }
        }
    } else {
        // v transposed: vo[bh][c][t0..t0+3] -- t0 multiple of 4, 8B-aligned
        #pragma unroll
        for (int m = 0; m < 4; ++m) {
            const int grow0 = mW + m * 16 + lg * 4;
            const int b = grow0 >> 11, t0 = grow0 & (NT - 1);
            #pragma unroll
            for (int n = 0; n < 2; ++n) {
                const int gcol = nW + n * 16 + lr;
                const int h = gcol / ND, c = gcol - h * ND;
                ushort4 pk;
                pk.x = f2bf(acc[m][n][0]); pk.y = f2bf(acc[m][n][1]);
                pk.z = f2bf(acc[m][n][2]); pk.w = f2bf(acc[m][n][3]);
                *reinterpret_cast<ushort4*>(
                    vo + ((size_t)(b * NH + h) * ND + c) * NT + t0) = pk;
            }
        }
    }
}

// ---------------------------------------------------------------------------
// Kernel 3: output projection via split-bf16 MFMA. out = att @ Wp + bp (fp32).
// ---------------------------------------------------------------------------
__global__ __launch_bounds__(256) void proj_mfma_kernel(
    const unsigned short* __restrict__ ah_g, const unsigned short* __restrict__ al_g,
    const unsigned short* __restrict__ bth, const unsigned short* __restrict__ btl,
    const float* __restrict__ bias, float* __restrict__ out)
{
    __shared__ unsigned short Ah[128 * 32], Al[128 * 32];
    __shared__ unsigned short Bh[64 * 32],  Bl[64 * 32];
    const int tid = threadIdx.x;
    const int l  = tid & 63, w = tid >> 6;
    const int lg = l >> 4,  lr = l & 15;
    const int wr = w >> 1,  wc = w & 1;
    const int rowBase = blockIdx.y * 128;
    const int colBase = blockIdx.x * 64;

    f32x4 acc[4][2];
    #pragma unroll
    for (int m = 0; m < 4; ++m)
        #pragma unroll
        for (int n = 0; n < 2; ++n) acc[m][n] = (f32x4){0.f, 0.f, 0.f, 0.f};

    for (int k0 = 0; k0 < NC; k0 += 32) {
        __syncthreads();
        #pragma unroll
        for (int i = 0; i < 2; ++i) {
            const int p   = w * 64 + 256 * i + l;
            const int row = p >> 2, ps = p & 3;
            const int u   = ps ^ ((row >> 1) & 3);
            const size_t src = (size_t)(rowBase + row) * NC + k0 + u * 8;
            const int dst = (w * 64 + 256 * i) * 8;
            gl_lds16(ah_g + src, Ah + dst);
            gl_lds16(al_g + src, Al + dst);
        }
        {
            const int p   = w * 64 + l;
            const int row = p >> 2, ps = p & 3;
            const int u   = ps ^ ((row >> 1) & 3);
            const size_t src = (size_t)(colBase + row) * NC + k0 + u * 8;
            gl_lds16(bth + src, Bh + w * 512);
            gl_lds16(btl + src, Bl + w * 512);
        }
        __syncthreads();

        bf16x8 a_h[4], a_l[4], b_h[2], b_l[2];
        #pragma unroll
        for (int m = 0; m < 4; ++m) {
            const int row = wr * 64 + m * 16 + lr;
            const int s   = sw_slot(row, lg) * 8;
            a_h[m] = *reinterpret_cast<const bf16x8*>(Ah + s);
            a_l[m] = *reinterpret_cast<const bf16x8*>(Al + s);
        }
        #pragma unroll
        for (int n = 0; n < 2; ++n) {
            const int row = wc * 32 + n * 16 + lr;
            const int s   = sw_slot(row, lg) * 8;
            b_h[n] = *reinterpret_cast<const bf16x8*>(Bh + s);
            b_l[n] = *reinterpret_cast<const bf16x8*>(Bl + s);
        }
        #pragma unroll
        for (int m = 0; m < 4; ++m)
            #pragma unroll
            for (int n = 0; n < 2; ++n) {
                acc[m][n] = __builtin_amdgcn_mfma_f32_16x16x32_bf16(
                    a_h[m], b_h[n], acc[m][n], 0, 0, 0);
                acc[m][n] = __builtin_amdgcn_mfma_f32_16x16x32_bf16(
                    a_h[m], b_l[n], acc[m][n], 0, 0, 0);
                acc[m][n] = __builtin_amdgcn_mfma_f32_16x16x32_bf16(
                    a_l[m], b_h[n], acc[m][n], 0, 0, 0);
            }
    }

    const int mW = rowBase + wr * 64;
    const int nW = colBase + wc * 32;
    #pragma unroll
    for (int n = 0; n < 2; ++n) {
        const int gcol = nW + n * 16 + lr;
        const float bv = bias[gcol];
        #pragma unroll
        for (int m = 0; m < 4; ++m) {
            #pragma unroll
            for (int r = 0; r < 4; ++r) {
                const int grow = mW + m * 16 + lg * 4 + r;
                out[(size_t)grow * NC + gcol] = acc[m][n][r] + bv;
            }
        }
    }
}

// ---------------------------------------------------------------------------
// Kernel 2: causal flash attention, bf16 MFMA (16x16x32), fp32 softmax.
// Identical to the HW-validated round-3 kernel except the epilogue emits
// bf16 hi/lo att for the MFMA output projection.
// ---------------------------------------------------------------------------
__global__ __launch_bounds__(256) void attn_mfma_kernel(
    const unsigned short* __restrict__ q, const unsigned short* __restrict__ k,
    const unsigned short* __restrict__ vt,
    unsigned short* __restrict__ att_h, unsigned short* __restrict__ att_l)
{
    const int qb = (gridDim.x - 1 - blockIdx.x) * 64;   // big tiles first
    const int bh = blockIdx.y;
    const int b  = bh >> 3;
    const int h  = bh & 7;

    const int tid = threadIdx.x;
    const int w   = tid >> 6;
    const int l   = tid & 63;
    const int lg  = l >> 4;
    const int lr  = l & 15;

    __shared__ unsigned short Ks [64 * 64];
    __shared__ unsigned short Vts[64 * 64];
    __shared__ unsigned short Pl[4][16 * 64];

    const unsigned short* __restrict__ Qg = q  + (size_t)bh * NT * ND;
    const unsigned short* __restrict__ Kg = k  + (size_t)bh * NT * ND;
    const unsigned short* __restrict__ Vg = vt + (size_t)bh * ND * NT;

    bf16x8 qf[2];
    {
        const int row = qb + w * 16 + lr;
        #pragma unroll
        for (int hh = 0; hh < 2; ++hh) {
            const int d0 = hh * 32 + lg * 8;
            bf16x8 tmp = {0, 0, 0, 0, 0, 0, 0, 0};
            if (d0 < ND)
                tmp = *reinterpret_cast<const bf16x8*>(Qg + (size_t)row * ND + d0);
            qf[hh] = tmp;
        }
    }

    const f32x4 fzero = {0.f, 0.f, 0.f, 0.f};
    f32x4 o[4];
    #pragma unroll
    for (int n = 0; n < 4; ++n) o[n] = fzero;
    float mrun[4] = {-INFINITY, -INFINITY, -INFINITY, -INFINITY};
    float lrun[4] = {0.f, 0.f, 0.f, 0.f};

    for (int kb = 0; kb <= qb; kb += 64) {
        __syncthreads();
        #pragma unroll
        for (int cc = 0; cc < 2; ++cc) {
            const int ch  = tid + cc * 256;
            const int row = ch >> 3;
            const int u   = ch & 7;
            uint4 kv = make_uint4(0u, 0u, 0u, 0u);
            uint4 vv = make_uint4(0u, 0u, 0u, 0u);
            if (u < 7)
                kv = *reinterpret_cast<const uint4*>(
                    Kg + (size_t)(kb + row) * ND + u * 8);
            if (row < ND)
                vv = *reinterpret_cast<const uint4*>(
                    Vg + (size_t)row * NT + kb + u * 8);
            *reinterpret_cast<uint4*>(Ks  + (row * 8 + (u ^ (row & 7))) * 8) = kv;
            *reinterpret_cast<uint4*>(Vts + (row * 8 + (u ^ (row & 7))) * 8) = vv;
        }
        __syncthreads();

        f32x4 s[4];
        #pragma unroll
        for (int n = 0; n < 4; ++n) {
            const int krow = n * 16 + lr;
            const bf16x8 kf0 = *reinterpret_cast<const bf16x8*>(
                Ks + (krow * 8 + ((0 + lg) ^ (krow & 7))) * 8);
            const bf16x8 kf1 = *reinterpret_cast<const bf16x8*>(
                Ks + (krow * 8 + ((4 + lg) ^ (krow & 7))) * 8);
            f32x4 acc = fzero;
            acc = __builtin_amdgcn_mfma_f32_16x16x32_bf16(qf[0], kf0, acc, 0, 0, 0);
            acc = __builtin_amdgcn_mfma_f32_16x16x32_bf16(qf[1], kf1, acc, 0, 0, 0);
            s[n] = acc;
        }

        #pragma unroll
        for (int n = 0; n < 4; ++n) {
            #pragma unroll
            for (int r = 0; r < 4; ++r) s[n][r] *= SCALE;
        }
        if (kb == qb) {
            #pragma unroll
            for (int n = 0; n < 4; ++n) {
                const int key = n * 16 + lr;
                #pragma unroll
                for (int r = 0; r < 4; ++r) {
                    const int qr = w * 16 + lg * 4 + r;
                    if (key > qr) s[n][r] = -1e30f;
                }
            }
        }

        float alpha[4];
        #pragma unroll
        for (int r = 0; r < 4; ++r) {
            float tmax = fmaxf(fmaxf(s[0][r], s[1][r]), fmaxf(s[2][r], s[3][r]));
            tmax = fmaxf(tmax, __shfl_xor(tmax, 1));
            tmax = fmaxf(tmax, __shfl_xor(tmax, 2));
            tmax = fmaxf(tmax, __shfl_xor(tmax, 4));
            tmax = fmaxf(tmax, __shfl_xor(tmax, 8));
            const float mnew = fmaxf(mrun[r], tmax);
            alpha[r] = __expf(mrun[r] - mnew);
            mrun[r]  = mnew;
            float tsum = 0.f;
            #pragma unroll
            for (int n = 0; n < 4; ++n) {
                const float p = __expf(s[n][r] - mnew);
                s[n][r] = p;
                tsum += p;
            }
            tsum += __shfl_xor(tsum, 1);
            tsum += __shfl_xor(tsum, 2);
            tsum += __shfl_xor(tsum, 4);
            tsum += __shfl_xor(tsum, 8);
            lrun[r] = lrun[r] * alpha[r] + tsum;
        }
        #pragma unroll
        for (int n = 0; n < 4; ++n) {
            #pragma unroll
            for (int r = 0; r < 4; ++r) o[n][r] *= alpha[r];
        }

        unsigned short* Pw = Pl[w];
        #pragma unroll
        for (int n = 0; n < 4; ++n) {
            const int u = n * 2 + (lr >> 3);
            #pragma unroll
            for (int r = 0; r < 4; ++r) {
                const int prow = lg * 4 + r;
                Pw[(prow * 8 + (u ^ (prow & 7))) * 8 + (lr & 7)] = f2bf(s[n][r]);
            }
        }
        const bf16x8 pf0 = *reinterpret_cast<const bf16x8*>(
            Pw + (lr * 8 + ((0 + lg) ^ (lr & 7))) * 8);
        const bf16x8 pf1 = *reinterpret_cast<const bf16x8*>(
            Pw + (lr * 8 + ((4 + lg) ^ (lr & 7))) * 8);

        #pragma unroll
        for (int n = 0; n < 4; ++n) {
            const int vrow = n * 16 + lr;
            const bf16x8 vf0 = *reinterpret_cast<const bf16x8*>(
                Vts + (vrow * 8 + ((0 + lg) ^ (vrow & 7))) * 8);
            const bf16x8 vf1 = *reinterpret_cast<const bf16x8*>(
                Vts + (vrow * 8 + ((4 + lg) ^ (vrow & 7))) * 8);
            o[n] = __builtin_amdgcn_mfma_f32_16x16x32_bf16(pf0, vf0, o[n], 0, 0, 0);
            o[n] = __builtin_amdgcn_mfma_f32_16x16x32_bf16(pf1, vf1, o[n], 0, 0, 0);
        }
    }

    // epilogue: normalize, emit bf16 hi/lo att [B][T][C]
    #pragma unroll
    for (int r = 0; r < 4; ++r) {
        const float inv = 1.0f / lrun[r];
        const int trow = qb + w * 16 + lg * 4 + r;
        const size_t rbase = ((size_t)b * NT + trow) * NC + h * ND;
        #pragma unroll
        for (int n = 0; n < 4; ++n) {
            const int c = n * 16 + lr;
            if (c < ND) {
                const float val = o[n][r] * inv;
                const unsigned short hh = f2bf(val);
                att_h[rbase + c] = hh;
                att_l[rbase + c] = f2bf(val - bf2f(hh));
            }
        }
    }
}

// ---------------------------------------------------------------------------
extern "C" void kernel_launch(void* const* d_in, const int* in_sizes, int n_in,
                              void* d_out, int out_size, void* d_ws, size_t ws_size,
                              hipStream_t stream)
{
    const float* x  = (const float*)d_in[0];
    const float* Wq = (const float*)d_in[1];
    const float* Wk = (const float*)d_in[2];
    const float* Wv = (const float*)d_in[3];
    const float* Wp = (const float*)d_in[4];
    const float* bp = (const float*)d_in[5];
    float* out = (float*)d_out;

    const size_t BTC = (size_t)NM * NC;        // 3,670,016
    const size_t WSZ = (size_t)NC * NC;        // 200,704
    unsigned short* p = (unsigned short*)d_ws;
    unsigned short* xh  = p;            p += BTC;
    unsigned short* xl  = p;            p += BTC;
    unsigned short* wth = p;            p += 4 * WSZ;   // q,k,v,p transposed hi
    unsigned short* wtl = p;            p += 4 * WSZ;
    unsigned short* qw  = p;            p += BTC;
    unsigned short* kw  = p;            p += BTC;
    unsigned short* vtw = p;            p += BTC;
    unsigned short* ath = p;            p += BTC;
    unsigned short* atl = p;            p += BTC;

    dim3 blk(256);
    conv_x_kernel<<<dim3((unsigned)(BTC / 1024)), blk, 0, stream>>>(x, xh, xl);
    conv_wt_kernel<<<dim3(NC / 32, NC / 32, 4), blk, 0, stream>>>(
        Wq, Wk, Wv, Wp, wth, wtl);
    qkv_mfma_kernel<<<dim3(NC / 64, NM / 128, 3), blk, 0, stream>>>(
        xh, xl, wth, wtl, qw, kw, vtw);
    attn_mfma_kernel<<<dim3(NT / 64, NB * NH), blk, 0, stream>>>(
        qw, kw, vtw, ath, atl);
    proj_mfma_kernel<<<dim3(NC / 64, NM / 128, 1), blk, 0, stream>>>(
        ath, atl, wth + 3 * WSZ, wtl + 3 * WSZ, bp, out);
}

// Round 10
// 267.845 us; speedup vs baseline: 3.9813x; 1.1322x over previous
//
#include <hip/hip_runtime.h>
#include <math.h>

// Problem constants (B=4, T=2048, C=448, H=8, d=56)
#define NB 4
#define NT 2048
#define NC 448
#define NH 8
#define ND 56
#define NM (NB * NT)          // 8192 rows
#define SCALE 0.04724555912615705f  // 1/sqrt(448)

typedef __attribute__((ext_vector_type(8))) short bf16x8;
typedef __attribute__((ext_vector_type(4))) float f32x4;

__device__ __forceinline__ unsigned short f2bf(float f) {
    unsigned u = __float_as_uint(f);
    u += 0x7fffu + ((u >> 16) & 1u);       // round-to-nearest-even
    return (unsigned short)(u >> 16);
}
__device__ __forceinline__ float bf2f(unsigned short h) {
    return __uint_as_float(((unsigned)h) << 16);
}

// async global->LDS, 16B per lane; lds dest must be wave-uniform base
__device__ __forceinline__ void gl_lds16(const unsigned short* g, unsigned short* l) {
    __builtin_amdgcn_global_load_lds(
        (const __attribute__((address_space(1))) unsigned int*)g,
        (__attribute__((address_space(3))) unsigned int*)l,
        16, 0, 0);
}

// swizzled 16B-slot index inside a [rows][32-bf16] tile (4 slots/row)
__device__ __forceinline__ int sw_slot(int row, int u) {
    return row * 4 + (u ^ ((row >> 1) & 3));
}

// ---------------------------------------------------------------------------
// Kernel 0a: x (fp32 [8192][448]) -> xh, xl (bf16 hi/lo, same layout)
// ---------------------------------------------------------------------------
__global__ __launch_bounds__(256) void conv_x_kernel(
    const float* __restrict__ x, unsigned short* __restrict__ xh,
    unsigned short* __restrict__ xl)
{
    const size_t i4 = ((size_t)blockIdx.x * 256 + threadIdx.x) * 4;
    const float4 v = *reinterpret_cast<const float4*>(x + i4);
    ushort4 h, l;
    h.x = f2bf(v.x); l.x = f2bf(v.x - bf2f(h.x));
    h.y = f2bf(v.y); l.y = f2bf(v.y - bf2f(h.y));
    h.z = f2bf(v.z); l.z = f2bf(v.z - bf2f(h.z));
    h.w = f2bf(v.w); l.w = f2bf(v.w - bf2f(h.w));
    *reinterpret_cast<ushort4*>(xh + i4) = h;
    *reinterpret_cast<ushort4*>(xl + i4) = l;
}

// ---------------------------------------------------------------------------
// Kernel 0b: W (fp32 [K=448][N=448]) -> Wt hi/lo (bf16 [N][K], transposed).
// z selects {Wq, Wk, Wv, Wp}. 32x32 LDS tile transpose, block 256 (32x8).
// ---------------------------------------------------------------------------
__global__ __launch_bounds__(256) void conv_wt_kernel(
    const float* __restrict__ Wq, const float* __restrict__ Wk,
    const float* __restrict__ Wv, const float* __restrict__ Wp,
    unsigned short* __restrict__ wth, unsigned short* __restrict__ wtl)
{
    const int z = blockIdx.z;
    const float* __restrict__ W =
        (z == 0) ? Wq : ((z == 1) ? Wk : ((z == 2) ? Wv : Wp));
    unsigned short* __restrict__ oh = wth + (size_t)z * NC * NC;
    unsigned short* __restrict__ ol = wtl + (size_t)z * NC * NC;

    __shared__ float t[32][33];
    const int tx = threadIdx.x & 31;
    const int ty = threadIdx.x >> 5;         // 0..7
    const int x0 = blockIdx.x * 32;          // n base (src cols)
    const int y0 = blockIdx.y * 32;          // k base (src rows)

    #pragma unroll
    for (int i = 0; i < 4; ++i)
        t[ty + i * 8][tx] = W[(size_t)(y0 + ty + i * 8) * NC + x0 + tx];
    __syncthreads();
    #pragma unroll
    for (int i = 0; i < 4; ++i) {
        const int n = x0 + ty + i * 8;
        const int k = y0 + tx;
        const float v = t[tx][ty + i * 8];
        const unsigned short h = f2bf(v);
        oh[(size_t)n * NC + k] = h;
        ol[(size_t)n * NC + k] = f2bf(v - bf2f(h));
    }
}

// ---------------------------------------------------------------------------
// Kernel 1: QKV projection via split-bf16 MFMA (ah*bh + ah*bl + al*bh).
// ---------------------------------------------------------------------------
__global__ __launch_bounds__(256) void qkv_mfma_kernel(
    const unsigned short* __restrict__ xh, const unsigned short* __restrict__ xl,
    const unsigned short* __restrict__ wth, const unsigned short* __restrict__ wtl,
    unsigned short* __restrict__ qo, unsigned short* __restrict__ ko,
    unsigned short* __restrict__ vo)
{
    const int z = blockIdx.z;
    const unsigned short* __restrict__ BTH = wth + (size_t)z * NC * NC;
    const unsigned short* __restrict__ BTL = wtl + (size_t)z * NC * NC;

    __shared__ unsigned short Ah[128 * 32], Al[128 * 32];
    __shared__ unsigned short Bh[64 * 32],  Bl[64 * 32];
    const int tid = threadIdx.x;
    const int l  = tid & 63, w = tid >> 6;
    const int lg = l >> 4,  lr = l & 15;
    const int wr = w >> 1,  wc = w & 1;
    const int rowBase = blockIdx.y * 128;
    const int colBase = blockIdx.x * 64;

    f32x4 acc[4][2];
    #pragma unroll
    for (int m = 0; m < 4; ++m)
        #pragma unroll
        for (int n = 0; n < 2; ++n) acc[m][n] = (f32x4){0.f, 0.f, 0.f, 0.f};

    for (int k0 = 0; k0 < NC; k0 += 32) {
        __syncthreads();
        #pragma unroll
        for (int i = 0; i < 2; ++i) {
            const int p   = w * 64 + 256 * i + l;
            const int row = p >> 2, ps = p & 3;
            const int u   = ps ^ ((row >> 1) & 3);
            const size_t src = (size_t)(rowBase + row) * NC + k0 + u * 8;
            const int dst = (w * 64 + 256 * i) * 8;     // ush elems, wave-uniform
            gl_lds16(xh + src, Ah + dst);
            gl_lds16(xl + src, Al + dst);
        }
        {
            const int p   = w * 64 + l;
            const int row = p >> 2, ps = p & 3;
            const int u   = ps ^ ((row >> 1) & 3);
            const size_t src = (size_t)(colBase + row) * NC + k0 + u * 8;
            gl_lds16(BTH + src, Bh + w * 512);
            gl_lds16(BTL + src, Bl + w * 512);
        }
        __syncthreads();

        bf16x8 a_h[4], a_l[4], b_h[2], b_l[2];
        #pragma unroll
        for (int m = 0; m < 4; ++m) {
            const int row = wr * 64 + m * 16 + lr;
            const int s   = sw_slot(row, lg) * 8;
            a_h[m] = *reinterpret_cast<const bf16x8*>(Ah + s);
            a_l[m] = *reinterpret_cast<const bf16x8*>(Al + s);
        }
        #pragma unroll
        for (int n = 0; n < 2; ++n) {
            const int row = wc * 32 + n * 16 + lr;
            const int s   = sw_slot(row, lg) * 8;
            b_h[n] = *reinterpret_cast<const bf16x8*>(Bh + s);
            b_l[n] = *reinterpret_cast<const bf16x8*>(Bl + s);
        }
        #pragma unroll
        for (int m = 0; m < 4; ++m)
            #pragma unroll
            for (int n = 0; n < 2; ++n) {
                acc[m][n] = __builtin_amdgcn_mfma_f32_16x16x32_bf16(
                    a_h[m], b_h[n], acc[m][n], 0, 0, 0);
                acc[m][n] = __builtin_amdgcn_mfma_f32_16x16x32_bf16(
                    a_h[m], b_l[n], acc[m][n], 0, 0, 0);
                acc[m][n] = __builtin_amdgcn_mfma_f32_16x16x32_bf16(
                    a_l[m], b_h[n], acc[m][n], 0, 0, 0);
            }
    }

    // Epilogue: D row=(lg*4+reg), col=lr within each 16x16 frag (m89 layout).
    const int mW = rowBase + wr * 64;
    const int nW = colBase + wc * 32;
    if (z < 2) {
        unsigned short* __restrict__ dst = (z == 0) ? qo : ko;
        #pragma unroll
        for (int m = 0; m < 4; ++m) {
            #pragma unroll
            for (int n = 0; n < 2; ++n) {
                const int gcol = nW + n * 16 + lr;
                const int h = gcol / ND, c = gcol - h * ND;
                #pragma unroll
                for (int r = 0; r < 4; ++r) {
                    const int grow = mW + m * 16 + lg * 4 + r;
                    const int b = grow >> 11, t = grow & (NT - 1);
                    dst[((size_t)(b * NH + h) * NT + t) * ND + c] =
                        f2bf(acc[m][n][r]);
                }
            }
        }
    } else {
        // v transposed: vo[bh][c][t0..t0+3] -- t0 multiple of 4, 8B-aligned
        #pragma unroll
        for (int m = 0; m < 4; ++m) {
            const int grow0 = mW + m * 16 + lg * 4;
            const int b = grow0 >> 11, t0 = grow0 & (NT - 1);
            #pragma unroll
            for (int n = 0; n < 2; ++n) {
                const int gcol = nW + n * 16 + lr;
                const int h = gcol / ND, c = gcol - h * ND;
                ushort4 pk;
                pk.x = f2bf(acc[m][n][0]); pk.y = f2bf(acc[m][n][1]);
                pk.z = f2bf(acc[m][n][2]); pk.w = f2bf(acc[m][n][3]);
                *reinterpret_cast<ushort4*>(
                    vo + ((size_t)(b * NH + h) * ND + c) * NT + t0) = pk;
            }
        }
    }
}

// ---------------------------------------------------------------------------
// Kernel 3: output projection via split-bf16 MFMA. out = att @ Wp + bp (fp32).
// ---------------------------------------------------------------------------
__global__ __launch_bounds__(256) void proj_mfma_kernel(
    const unsigned short* __restrict__ ah_g, const unsigned short* __restrict__ al_g,
    const unsigned short* __restrict__ bth, const unsigned short* __restrict__ btl,
    const float* __restrict__ bias, float* __restrict__ out)
{
    __shared__ unsigned short Ah[128 * 32], Al[128 * 32];
    __shared__ unsigned short Bh[64 * 32],  Bl[64 * 32];
    const int tid = threadIdx.x;
    const int l  = tid & 63, w = tid >> 6;
    const int lg = l >> 4,  lr = l & 15;
    const int wr = w >> 1,  wc = w & 1;
    const int rowBase = blockIdx.y * 128;
    const int colBase = blockIdx.x * 64;

    f32x4 acc[4][2];
    #pragma unroll
    for (int m = 0; m < 4; ++m)
        #pragma unroll
        for (int n = 0; n < 2; ++n) acc[m][n] = (f32x4){0.f, 0.f, 0.f, 0.f};

    for (int k0 = 0; k0 < NC; k0 += 32) {
        __syncthreads();
        #pragma unroll
        for (int i = 0; i < 2; ++i) {
            const int p   = w * 64 + 256 * i + l;
            const int row = p >> 2, ps = p & 3;
            const int u   = ps ^ ((row >> 1) & 3);
            const size_t src = (size_t)(rowBase + row) * NC + k0 + u * 8;
            const int dst = (w * 64 + 256 * i) * 8;
            gl_lds16(ah_g + src, Ah + dst);
            gl_lds16(al_g + src, Al + dst);
        }
        {
            const int p   = w * 64 + l;
            const int row = p >> 2, ps = p & 3;
            const int u   = ps ^ ((row >> 1) & 3);
            const size_t src = (size_t)(colBase + row) * NC + k0 + u * 8;
            gl_lds16(bth + src, Bh + w * 512);
            gl_lds16(btl + src, Bl + w * 512);
        }
        __syncthreads();

        bf16x8 a_h[4], a_l[4], b_h[2], b_l[2];
        #pragma unroll
        for (int m = 0; m < 4; ++m) {
            const int row = wr * 64 + m * 16 + lr;
            const int s   = sw_slot(row, lg) * 8;
            a_h[m] = *reinterpret_cast<const bf16x8*>(Ah + s);
            a_l[m] = *reinterpret_cast<const bf16x8*>(Al + s);
        }
        #pragma unroll
        for (int n = 0; n < 2; ++n) {
            const int row = wc * 32 + n * 16 + lr;
            const int s   = sw_slot(row, lg) * 8;
            b_h[n] = *reinterpret_cast<const bf16x8*>(Bh + s);
            b_l[n] = *reinterpret_cast<const bf16x8*>(Bl + s);
        }
        #pragma unroll
        for (int m = 0; m < 4; ++m)
            #pragma unroll
            for (int n = 0; n < 2; ++n) {
                acc[m][n] = __builtin_amdgcn_mfma_f32_16x16x32_bf16(
                    a_h[m], b_h[n], acc[m][n], 0, 0, 0);
                acc[m][n] = __builtin_amdgcn_mfma_f32_16x16x32_bf16(
                    a_h[m], b_l[n], acc[m][n], 0, 0, 0);
                acc[m][n] = __builtin_amdgcn_mfma_f32_16x16x32_bf16(
                    a_l[m], b_h[n], acc[m][n], 0, 0, 0);
            }
    }

    const int mW = rowBase + wr * 64;
    const int nW = colBase + wc * 32;
    #pragma unroll
    for (int n = 0; n < 2; ++n) {
        const int gcol = nW + n * 16 + lr;
        const float bv = bias[gcol];
        #pragma unroll
        for (int m = 0; m < 4; ++m) {
            #pragma unroll
            for (int r = 0; r < 4; ++r) {
                const int grow = mW + m * 16 + lg * 4 + r;
                out[(size_t)grow * NC + gcol] = acc[m][n][r] + bv;
            }
        }
    }
}

// ---------------------------------------------------------------------------
// Kernel 2: causal flash attention, bf16 MFMA, fp32 merged online softmax.
// KVBLK=128 (2x64 subtiles/round), register-prefetch pipeline:
//   write staged regs->LDS / barrier / prefetch next round to regs /
//   QK^T(A,B) / merged softmax / PV(A), PV(B) / barrier.
// All fragment layouts identical to the HW-validated round-4 kernel.
// ---------------------------------------------------------------------------
__global__ __launch_bounds__(256) void attn_mfma_kernel(
    const unsigned short* __restrict__ q, const unsigned short* __restrict__ k,
    const unsigned short* __restrict__ vt,
    unsigned short* __restrict__ att_h, unsigned short* __restrict__ att_l)
{
    const int qb = (gridDim.x - 1 - blockIdx.x) * 64;   // big tiles first
    const int bh = blockIdx.y;
    const int b  = bh >> 3;
    const int h  = bh & 7;

    const int tid = threadIdx.x;
    const int w   = tid >> 6;
    const int l   = tid & 63;
    const int lg  = l >> 4;
    const int lr  = l & 15;

    __shared__ unsigned short Ks [2][64 * 64];   // 16 KiB (key x d)
    __shared__ unsigned short Vts[2][64 * 64];   // 16 KiB (d x key)
    __shared__ unsigned short Pl[4][16 * 64];    // 8 KiB per-wave P

    const unsigned short* __restrict__ Qg = q  + (size_t)bh * NT * ND;
    const unsigned short* __restrict__ Kg = k  + (size_t)bh * NT * ND;
    const unsigned short* __restrict__ Vg = vt + (size_t)bh * ND * NT;

    // Q fragments (A-operand), held across the whole kv loop.
    bf16x8 qf[2];
    {
        const int row = qb + w * 16 + lr;
        #pragma unroll
        for (int hh = 0; hh < 2; ++hh) {
            const int d0 = hh * 32 + lg * 8;
            bf16x8 tmp = {0, 0, 0, 0, 0, 0, 0, 0};
            if (d0 < ND)
                tmp = *reinterpret_cast<const bf16x8*>(Qg + (size_t)row * ND + d0);
            qf[hh] = tmp;
        }
    }

    const f32x4 fzero = {0.f, 0.f, 0.f, 0.f};
    f32x4 o[4];
    #pragma unroll
    for (int n = 0; n < 4; ++n) o[n] = fzero;
    float mrun[4] = {-INFINITY, -INFINITY, -INFINITY, -INFINITY};
    float lrun[4] = {0.f, 0.f, 0.f, 0.f};

    // staging registers (next round's K/V)
    uint4 rK[2][2], rV[2][2];
    // prologue: load round kb=0
    #pragma unroll
    for (int s = 0; s < 2; ++s)
        #pragma unroll
        for (int cc = 0; cc < 2; ++cc) {
            const int ch = tid + cc * 256;
            const int row = ch >> 3, u = ch & 7;
            uint4 kvv = make_uint4(0u, 0u, 0u, 0u);
            uint4 vvv = make_uint4(0u, 0u, 0u, 0u);
            if (u < 7)
                kvv = *reinterpret_cast<const uint4*>(
                    Kg + (size_t)(s * 64 + row) * ND + u * 8);
            if (row < ND)
                vvv = *reinterpret_cast<const uint4*>(
                    Vg + (size_t)row * NT + s * 64 + u * 8);
            rK[s][cc] = kvv; rV[s][cc] = vvv;
        }

    for (int kb = 0; kb <= qb; kb += 128) {
        // ---- write staged regs to LDS (swizzled slots) ----
        #pragma unroll
        for (int s = 0; s < 2; ++s)
            #pragma unroll
            for (int cc = 0; cc < 2; ++cc) {
                const int ch = tid + cc * 256;
                const int row = ch >> 3, u = ch & 7;
                const int sl = (row * 8 + (u ^ (row & 7))) * 8;
                *reinterpret_cast<uint4*>(&Ks[s][sl])  = rK[s][cc];
                *reinterpret_cast<uint4*>(&Vts[s][sl]) = rV[s][cc];
            }
        __syncthreads();

        // ---- prefetch next round into regs (hidden under compute) ----
        if (kb + 128 <= qb) {
            #pragma unroll
            for (int s = 0; s < 2; ++s)
                #pragma unroll
                for (int cc = 0; cc < 2; ++cc) {
                    const int ch = tid + cc * 256;
                    const int row = ch >> 3, u = ch & 7;
                    uint4 kvv = make_uint4(0u, 0u, 0u, 0u);
                    uint4 vvv = make_uint4(0u, 0u, 0u, 0u);
                    if (u < 7)
                        kvv = *reinterpret_cast<const uint4*>(
                            Kg + (size_t)(kb + 128 + s * 64 + row) * ND + u * 8);
                    if (row < ND)
                        vvv = *reinterpret_cast<const uint4*>(
                            Vg + (size_t)row * NT + kb + 128 + s * 64 + u * 8);
                    rK[s][cc] = kvv; rV[s][cc] = vvv;
                }
        }

        // ---- QK^T both subtiles: S[16 q][128 key] per wave (16 MFMAs) ----
        f32x4 sc[2][4];
        __builtin_amdgcn_s_setprio(1);
        #pragma unroll
        for (int s = 0; s < 2; ++s)
            #pragma unroll
            for (int n = 0; n < 4; ++n) {
                const int krow = n * 16 + lr;
                const bf16x8 kf0 = *reinterpret_cast<const bf16x8*>(
                    &Ks[s][(krow * 8 + ((0 + lg) ^ (krow & 7))) * 8]);
                const bf16x8 kf1 = *reinterpret_cast<const bf16x8*>(
                    &Ks[s][(krow * 8 + ((4 + lg) ^ (krow & 7))) * 8]);
                f32x4 a = fzero;
                a = __builtin_amdgcn_mfma_f32_16x16x32_bf16(qf[0], kf0, a, 0, 0, 0);
                a = __builtin_amdgcn_mfma_f32_16x16x32_bf16(qf[1], kf1, a, 0, 0, 0);
                sc[s][n] = a;
            }
        __builtin_amdgcn_s_setprio(0);

        // scale + causal mask (elementwise on diagonal/overrun subtiles)
        #pragma unroll
        for (int s = 0; s < 2; ++s) {
            #pragma unroll
            for (int n = 0; n < 4; ++n)
                #pragma unroll
                for (int r = 0; r < 4; ++r) sc[s][n][r] *= SCALE;
            const int kbs = kb + s * 64;
            if (kbs + 63 > qb) {
                #pragma unroll
                for (int n = 0; n < 4; ++n) {
                    const int key = kbs + n * 16 + lr;
                    #pragma unroll
                    for (int r = 0; r < 4; ++r) {
                        const int qr = qb + w * 16 + lg * 4 + r;
                        if (key > qr) sc[s][n][r] = -1e30f;
                    }
                }
            }
        }

        // ---- merged online softmax over 128 keys ----
        float alpha[4];
        #pragma unroll
        for (int r = 0; r < 4; ++r) {
            float tmax = fmaxf(
                fmaxf(fmaxf(sc[0][0][r], sc[0][1][r]), fmaxf(sc[0][2][r], sc[0][3][r])),
                fmaxf(fmaxf(sc[1][0][r], sc[1][1][r]), fmaxf(sc[1][2][r], sc[1][3][r])));
            tmax = fmaxf(tmax, __shfl_xor(tmax, 1));
            tmax = fmaxf(tmax, __shfl_xor(tmax, 2));
            tmax = fmaxf(tmax, __shfl_xor(tmax, 4));
            tmax = fmaxf(tmax, __shfl_xor(tmax, 8));
            const float mnew = fmaxf(mrun[r], tmax);
            alpha[r] = __expf(mrun[r] - mnew);   // first round: exp(-inf)=0
            mrun[r]  = mnew;
            float tsum = 0.f;
            #pragma unroll
            for (int s = 0; s < 2; ++s)
                #pragma unroll
                for (int n = 0; n < 4; ++n) {
                    const float p = __expf(sc[s][n][r] - mnew);
                    sc[s][n][r] = p;
                    tsum += p;
                }
            tsum += __shfl_xor(tsum, 1);
            tsum += __shfl_xor(tsum, 2);
            tsum += __shfl_xor(tsum, 4);
            tsum += __shfl_xor(tsum, 8);
            lrun[r] = lrun[r] * alpha[r] + tsum;
        }
        #pragma unroll
        for (int n = 0; n < 4; ++n)
            #pragma unroll
            for (int r = 0; r < 4; ++r) o[n][r] *= alpha[r];

        // ---- PV per subtile (P pack -> wave-local LDS -> A-frags) ----
        unsigned short* Pw = Pl[w];
        #pragma unroll
        for (int s = 0; s < 2; ++s) {
            #pragma unroll
            for (int n = 0; n < 4; ++n) {
                const int u = n * 2 + (lr >> 3);
                #pragma unroll
                for (int r = 0; r < 4; ++r) {
                    const int prow = lg * 4 + r;
                    Pw[(prow * 8 + (u ^ (prow & 7))) * 8 + (lr & 7)] =
                        f2bf(sc[s][n][r]);
                }
            }
            const bf16x8 pf0 = *reinterpret_cast<const bf16x8*>(
                &Pw[(lr * 8 + ((0 + lg) ^ (lr & 7))) * 8]);
            const bf16x8 pf1 = *reinterpret_cast<const bf16x8*>(
                &Pw[(lr * 8 + ((4 + lg) ^ (lr & 7))) * 8]);
            __builtin_amdgcn_s_setprio(1);
            #pragma unroll
            for (int n = 0; n < 4; ++n) {
                const int vrow = n * 16 + lr;
                const bf16x8 vf0 = *reinterpret_cast<const bf16x8*>(
                    &Vts[s][(vrow * 8 + ((0 + lg) ^ (vrow & 7))) * 8]);
                const bf16x8 vf1 = *reinterpret_cast<const bf16x8*>(
                    &Vts[s][(vrow * 8 + ((4 + lg) ^ (vrow & 7))) * 8]);
                o[n] = __builtin_amdgcn_mfma_f32_16x16x32_bf16(pf0, vf0, o[n], 0, 0, 0);
                o[n] = __builtin_amdgcn_mfma_f32_16x16x32_bf16(pf1, vf1, o[n], 0, 0, 0);
            }
            __builtin_amdgcn_s_setprio(0);
        }
        __syncthreads();   // protect LDS before next round's writes
    }

    // ---- epilogue: normalize, emit bf16 hi/lo att [B][T][C] ----
    #pragma unroll
    for (int r = 0; r < 4; ++r) {
        const float inv = 1.0f / lrun[r];
        const int trow = qb + w * 16 + lg * 4 + r;
        const size_t rbase = ((size_t)b * NT + trow) * NC + h * ND;
        #pragma unroll
        for (int n = 0; n < 4; ++n) {
            const int c = n * 16 + lr;
            if (c < ND) {
                const float val = o[n][r] * inv;
                const unsigned short hh = f2bf(val);
                att_h[rbase + c] = hh;
                att_l[rbase + c] = f2bf(val - bf2f(hh));
            }
        }
    }
}

// ---------------------------------------------------------------------------
extern "C" void kernel_launch(void* const* d_in, const int* in_sizes, int n_in,
                              void* d_out, int out_size, void* d_ws, size_t ws_size,
                              hipStream_t stream)
{
    const float* x  = (const float*)d_in[0];
    const float* Wq = (const float*)d_in[1];
    const float* Wk = (const float*)d_in[2];
    const float* Wv = (const float*)d_in[3];
    const float* Wp = (const float*)d_in[4];
    const float* bp = (const float*)d_in[5];
    float* out = (float*)d_out;

    const size_t BTC = (size_t)NM * NC;        // 3,670,016
    const size_t WSZ = (size_t)NC * NC;        // 200,704
    unsigned short* p = (unsigned short*)d_ws;
    unsigned short* xh  = p;            p += BTC;
    unsigned short* xl  = p;            p += BTC;
    unsigned short* wth = p;            p += 4 * WSZ;   // q,k,v,p transposed hi
    unsigned short* wtl = p;            p += 4 * WSZ;
    unsigned short* qw  = p;            p += BTC;
    unsigned short* kw  = p;            p += BTC;
    unsigned short* vtw = p;            p += BTC;
    unsigned short* ath = p;            p += BTC;
    unsigned short* atl = p;            p += BTC;

    dim3 blk(256);
    conv_x_kernel<<<dim3((unsigned)(BTC / 1024)), blk, 0, stream>>>(x, xh, xl);
    conv_wt_kernel<<<dim3(NC / 32, NC / 32, 4), blk, 0, stream>>>(
        Wq, Wk, Wv, Wp, wth, wtl);
    qkv_mfma_kernel<<<dim3(NC / 64, NM / 128, 3), blk, 0, stream>>>(
        xh, xl, wth, wtl, qw, kw, vtw);
    attn_mfma_kernel<<<dim3(NT / 64, NB * NH), blk, 0, stream>>>(
        qw, kw, vtw, ath, atl);
    proj_mfma_kernel<<<dim3(NC / 64, NM / 128, 1), blk, 0, stream>>>(
        ath, atl, wth + 3 * WSZ, wtl + 3 * WSZ, bp, out);
}

// Round 12
// 226.773 us; speedup vs baseline: 4.7024x; 1.1811x over previous
//
#include <hip/hip_runtime.h>
#include <math.h>

// Problem constants (B=4, T=2048, C=448, H=8, d=56)
#define NB 4
#define NT 2048
#define NC 448
#define NH 8
#define ND 56
#define NM (NB * NT)          // 8192 rows
#define SCALE 0.04724555912615705f  // 1/sqrt(448)

typedef __attribute__((ext_vector_type(8))) short bf16x8;
typedef __attribute__((ext_vector_type(4))) float f32x4;

__device__ __forceinline__ unsigned short f2bf(float f) {
    unsigned u = __float_as_uint(f);
    u += 0x7fffu + ((u >> 16) & 1u);       // round-to-nearest-even
    return (unsigned short)(u >> 16);
}
__device__ __forceinline__ float bf2f(unsigned short h) {
    return __uint_as_float(((unsigned)h) << 16);
}

// async global->LDS, 16B per lane; lds dest must be wave-uniform base
__device__ __forceinline__ void gl_lds16(const unsigned short* g, unsigned short* l) {
    __builtin_amdgcn_global_load_lds(
        (const __attribute__((address_space(1))) unsigned int*)g,
        (__attribute__((address_space(3))) unsigned int*)l,
        16, 0, 0);
}

// swizzled 16B-slot index inside a [rows][32-bf16] tile (4 slots/row)
__device__ __forceinline__ int sw_slot(int row, int u) {
    return row * 4 + (u ^ ((row >> 1) & 3));
}

// ---------------------------------------------------------------------------
// Kernel 0a: x (fp32 [8192][448]) -> xh, xl (bf16 hi/lo, same layout)
// ---------------------------------------------------------------------------
__global__ __launch_bounds__(256) void conv_x_kernel(
    const float* __restrict__ x, unsigned short* __restrict__ xh,
    unsigned short* __restrict__ xl)
{
    const size_t i4 = ((size_t)blockIdx.x * 256 + threadIdx.x) * 4;
    const float4 v = *reinterpret_cast<const float4*>(x + i4);
    ushort4 h, l;
    h.x = f2bf(v.x); l.x = f2bf(v.x - bf2f(h.x));
    h.y = f2bf(v.y); l.y = f2bf(v.y - bf2f(h.y));
    h.z = f2bf(v.z); l.z = f2bf(v.z - bf2f(h.z));
    h.w = f2bf(v.w); l.w = f2bf(v.w - bf2f(h.w));
    *reinterpret_cast<ushort4*>(xh + i4) = h;
    *reinterpret_cast<ushort4*>(xl + i4) = l;
}

// ---------------------------------------------------------------------------
// Kernel 0b: W (fp32 [K=448][N=448]) -> Wt hi/lo (bf16 [N][K], transposed).
// z selects {Wq, Wk, Wv, Wp}. 32x32 LDS tile transpose, block 256 (32x8).
// ---------------------------------------------------------------------------
__global__ __launch_bounds__(256) void conv_wt_kernel(
    const float* __restrict__ Wq, const float* __restrict__ Wk,
    const float* __restrict__ Wv, const float* __restrict__ Wp,
    unsigned short* __restrict__ wth, unsigned short* __restrict__ wtl)
{
    const int z = blockIdx.z;
    const float* __restrict__ W =
        (z == 0) ? Wq : ((z == 1) ? Wk : ((z == 2) ? Wv : Wp));
    unsigned short* __restrict__ oh = wth + (size_t)z * NC * NC;
    unsigned short* __restrict__ ol = wtl + (size_t)z * NC * NC;

    __shared__ float t[32][33];
    const int tx = threadIdx.x & 31;
    const int ty = threadIdx.x >> 5;         // 0..7
    const int x0 = blockIdx.x * 32;          // n base (src cols)
    const int y0 = blockIdx.y * 32;          // k base (src rows)

    #pragma unroll
    for (int i = 0; i < 4; ++i)
        t[ty + i * 8][tx] = W[(size_t)(y0 + ty + i * 8) * NC + x0 + tx];
    __syncthreads();
    #pragma unroll
    for (int i = 0; i < 4; ++i) {
        const int n = x0 + ty + i * 8;
        const int k = y0 + tx;
        const float v = t[tx][ty + i * 8];
        const unsigned short h = f2bf(v);
        oh[(size_t)n * NC + k] = h;
        ol[(size_t)n * NC + k] = f2bf(v - bf2f(h));
    }
}

// ---------------------------------------------------------------------------
// Kernel 1: QKV projection via split-bf16 MFMA (ah*bh + ah*bl + al*bh).
// ---------------------------------------------------------------------------
__global__ __launch_bounds__(256) void qkv_mfma_kernel(
    const unsigned short* __restrict__ xh, const unsigned short* __restrict__ xl,
    const unsigned short* __restrict__ wth, const unsigned short* __restrict__ wtl,
    unsigned short* __restrict__ qo, unsigned short* __restrict__ ko,
    unsigned short* __restrict__ vo)
{
    const int z = blockIdx.z;
    const unsigned short* __restrict__ BTH = wth + (size_t)z * NC * NC;
    const unsigned short* __restrict__ BTL = wtl + (size_t)z * NC * NC;

    __shared__ unsigned short Ah[128 * 32], Al[128 * 32];
    __shared__ unsigned short Bh[64 * 32],  Bl[64 * 32];
    const int tid = threadIdx.x;
    const int l  = tid & 63, w = tid >> 6;
    const int lg = l >> 4,  lr = l & 15;
    const int wr = w >> 1,  wc = w & 1;
    const int rowBase = blockIdx.y * 128;
    const int colBase = blockIdx.x * 64;

    f32x4 acc[4][2];
    #pragma unroll
    for (int m = 0; m < 4; ++m)
        #pragma unroll
        for (int n = 0; n < 2; ++n) acc[m][n] = (f32x4){0.f, 0.f, 0.f, 0.f};

    for (int k0 = 0; k0 < NC; k0 += 32) {
        __syncthreads();
        #pragma unroll
        for (int i = 0; i < 2; ++i) {
            const int p   = w * 64 + 256 * i + l;
            const int row = p >> 2, ps = p & 3;
            const int u   = ps ^ ((row >> 1) & 3);
            const size_t src = (size_t)(rowBase + row) * NC + k0 + u * 8;
            const int dst = (w * 64 + 256 * i) * 8;     // ush elems, wave-uniform
            gl_lds16(xh + src, Ah + dst);
            gl_lds16(xl + src, Al + dst);
        }
        {
            const int p   = w * 64 + l;
            const int row = p >> 2, ps = p & 3;
            const int u   = ps ^ ((row >> 1) & 3);
            const size_t src = (size_t)(colBase + row) * NC + k0 + u * 8;
            gl_lds16(BTH + src, Bh + w * 512);
            gl_lds16(BTL + src, Bl + w * 512);
        }
        __syncthreads();

        bf16x8 a_h[4], a_l[4], b_h[2], b_l[2];
        #pragma unroll
        for (int m = 0; m < 4; ++m) {
            const int row = wr * 64 + m * 16 + lr;
            const int s   = sw_slot(row, lg) * 8;
            a_h[m] = *reinterpret_cast<const bf16x8*>(Ah + s);
            a_l[m] = *reinterpret_cast<const bf16x8*>(Al + s);
        }
        #pragma unroll
        for (int n = 0; n < 2; ++n) {
            const int row = wc * 32 + n * 16 + lr;
            const int s   = sw_slot(row, lg) * 8;
            b_h[n] = *reinterpret_cast<const bf16x8*>(Bh + s);
            b_l[n] = *reinterpret_cast<const bf16x8*>(Bl + s);
        }
        #pragma unroll
        for (int m = 0; m < 4; ++m)
            #pragma unroll
            for (int n = 0; n < 2; ++n) {
                acc[m][n] = __builtin_amdgcn_mfma_f32_16x16x32_bf16(
                    a_h[m], b_h[n], acc[m][n], 0, 0, 0);
                acc[m][n] = __builtin_amdgcn_mfma_f32_16x16x32_bf16(
                    a_h[m], b_l[n], acc[m][n], 0, 0, 0);
                acc[m][n] = __builtin_amdgcn_mfma_f32_16x16x32_bf16(
                    a_l[m], b_h[n], acc[m][n], 0, 0, 0);
            }
    }

    // Epilogue: D row=(lg*4+reg), col=lr within each 16x16 frag (m89 layout).
    const int mW = rowBase + wr * 64;
    const int nW = colBase + wc * 32;
    if (z < 2) {
        unsigned short* __restrict__ dst = (z == 0) ? qo : ko;
        #pragma unroll
        for (int m = 0; m < 4; ++m) {
            #pragma unroll
            for (int n = 0; n < 2; ++n) {
                const int gcol = nW + n * 16 + lr;
                const int h = gcol / ND, c = gcol - h * ND;
                #pragma unroll
                for (int r = 0; r < 4; ++r) {
                    const int grow = mW + m * 16 + lg * 4 + r;
                    const int b = grow >> 11, t = grow & (NT - 1);
                    dst[((size_t)(b * NH + h) * NT + t) * ND + c] =
                        f2bf(acc[m][n][r]);
                }
            }
        }
    } else {
        // v transposed: vo[bh][c][t0..t0+3] -- t0 multiple of 4, 8B-aligned
        #pragma unroll
        for (int m = 0; m < 4; ++m) {
            const int grow0 = mW + m * 16 + lg * 4;
            const int b = grow0 >> 11, t0 = grow0 & (NT - 1);
            #pragma unroll
            for (int n = 0; n < 2; ++n) {
                const int gcol = nW + n * 16 + lr;
                const int h = gcol / ND, c = gcol - h * ND;
                ushort4 pk;
                pk.x = f2bf(acc[m][n][0]); pk.y = f2bf(acc[m][n][1]);
                pk.z = f2bf(acc[m][n][2]); pk.w = f2bf(acc[m][n][3]);
                *reinterpret_cast<ushort4*>(
                    vo + ((size_t)(b * NH + h) * ND + c) * NT + t0) = pk;
            }
        }
    }
}

// ---------------------------------------------------------------------------
// Kernel 3: output projection via split-bf16 MFMA. out = att @ Wp + bp (fp32).
// ---------------------------------------------------------------------------
__global__ __launch_bounds__(256) void proj_mfma_kernel(
    const unsigned short* __restrict__ ah_g, const unsigned short* __restrict__ al_g,
    const unsigned short* __restrict__ bth, const unsigned short* __restrict__ btl,
    const float* __restrict__ bias, float* __restrict__ out)
{
    __shared__ unsigned short Ah[128 * 32], Al[128 * 32];
    __shared__ unsigned short Bh[64 * 32],  Bl[64 * 32];
    const int tid = threadIdx.x;
    const int l  = tid & 63, w = tid >> 6;
    const int lg = l >> 4,  lr = l & 15;
    const int wr = w >> 1,  wc = w & 1;
    const int rowBase = blockIdx.y * 128;
    const int colBase = blockIdx.x * 64;

    f32x4 acc[4][2];
    #pragma unroll
    for (int m = 0; m < 4; ++m)
        #pragma unroll
        for (int n = 0; n < 2; ++n) acc[m][n] = (f32x4){0.f, 0.f, 0.f, 0.f};

    for (int k0 = 0; k0 < NC; k0 += 32) {
        __syncthreads();
        #pragma unroll
        for (int i = 0; i < 2; ++i) {
            const int p   = w * 64 + 256 * i + l;
            const int row = p >> 2, ps = p & 3;
            const int u   = ps ^ ((row >> 1) & 3);
            const size_t src = (size_t)(rowBase + row) * NC + k0 + u * 8;
            const int dst = (w * 64 + 256 * i) * 8;
            gl_lds16(ah_g + src, Ah + dst);
            gl_lds16(al_g + src, Al + dst);
        }
        {
            const int p   = w * 64 + l;
            const int row = p >> 2, ps = p & 3;
            const int u   = ps ^ ((row >> 1) & 3);
            const size_t src = (size_t)(colBase + row) * NC + k0 + u * 8;
            gl_lds16(bth + src, Bh + w * 512);
            gl_lds16(btl + src, Bl + w * 512);
        }
        __syncthreads();

        bf16x8 a_h[4], a_l[4], b_h[2], b_l[2];
        #pragma unroll
        for (int m = 0; m < 4; ++m) {
            const int row = wr * 64 + m * 16 + lr;
            const int s   = sw_slot(row, lg) * 8;
            a_h[m] = *reinterpret_cast<const bf16x8*>(Ah + s);
            a_l[m] = *reinterpret_cast<const bf16x8*>(Al + s);
        }
        #pragma unroll
        for (int n = 0; n < 2; ++n) {
            const int row = wc * 32 + n * 16 + lr;
            const int s   = sw_slot(row, lg) * 8;
            b_h[n] = *reinterpret_cast<const bf16x8*>(Bh + s);
            b_l[n] = *reinterpret_cast<const bf16x8*>(Bl + s);
        }
        #pragma unroll
        for (int m = 0; m < 4; ++m)
            #pragma unroll
            for (int n = 0; n < 2; ++n) {
                acc[m][n] = __builtin_amdgcn_mfma_f32_16x16x32_bf16(
                    a_h[m], b_h[n], acc[m][n], 0, 0, 0);
                acc[m][n] = __builtin_amdgcn_mfma_f32_16x16x32_bf16(
                    a_h[m], b_l[n], acc[m][n], 0, 0, 0);
                acc[m][n] = __builtin_amdgcn_mfma_f32_16x16x32_bf16(
                    a_l[m], b_h[n], acc[m][n], 0, 0, 0);
            }
    }

    const int mW = rowBase + wr * 64;
    const int nW = colBase + wc * 32;
    #pragma unroll
    for (int n = 0; n < 2; ++n) {
        const int gcol = nW + n * 16 + lr;
        const float bv = bias[gcol];
        #pragma unroll
        for (int m = 0; m < 4; ++m) {
            #pragma unroll
            for (int r = 0; r < 4; ++r) {
                const int grow = mW + m * 16 + lg * 4 + r;
                out[(size_t)grow * NC + gcol] = acc[m][n][r] + bv;
            }
        }
    }
}

// ---------------------------------------------------------------------------
// Kernel 2: causal flash attention, bf16 MFMA, fp32 merged online softmax.
// Grid (bh, qtile) -- bh INNER so co-scheduled blocks span different qtiles
// (load balance: per-CU work 28-40 rounds instead of 4-64) and same-XCD
// blocks share bh%8 K/V in L2. Deferred-scale softmax via fma.
// ---------------------------------------------------------------------------
__global__ __launch_bounds__(256) void attn_mfma_kernel(
    const unsigned short* __restrict__ q, const unsigned short* __restrict__ k,
    const unsigned short* __restrict__ vt,
    unsigned short* __restrict__ att_h, unsigned short* __restrict__ att_l)
{
    const int bh = blockIdx.x;                          // 0..31
    const int qb = (gridDim.y - 1 - blockIdx.y) * 64;   // big tiles first
    const int b  = bh >> 3;
    const int h  = bh & 7;

    const int tid = threadIdx.x;
    const int w   = tid >> 6;
    const int l   = tid & 63;
    const int lg  = l >> 4;
    const int lr  = l & 15;

    __shared__ unsigned short Ks [2][64 * 64];   // 16 KiB (key x d)
    __shared__ unsigned short Vts[2][64 * 64];   // 16 KiB (d x key)
    __shared__ unsigned short Pl[4][16 * 64];    // 8 KiB per-wave P

    const unsigned short* __restrict__ Qg = q  + (size_t)bh * NT * ND;
    const unsigned short* __restrict__ Kg = k  + (size_t)bh * NT * ND;
    const unsigned short* __restrict__ Vg = vt + (size_t)bh * ND * NT;

    // Q fragments (A-operand), held across the whole kv loop.
    bf16x8 qf[2];
    {
        const int row = qb + w * 16 + lr;
        #pragma unroll
        for (int hh = 0; hh < 2; ++hh) {
            const int d0 = hh * 32 + lg * 8;
            bf16x8 tmp = {0, 0, 0, 0, 0, 0, 0, 0};
            if (d0 < ND)
                tmp = *reinterpret_cast<const bf16x8*>(Qg + (size_t)row * ND + d0);
            qf[hh] = tmp;
        }
    }

    const f32x4 fzero = {0.f, 0.f, 0.f, 0.f};
    f32x4 o[4];
    #pragma unroll
    for (int n = 0; n < 4; ++n) o[n] = fzero;
    float mrun[4] = {-INFINITY, -INFINITY, -INFINITY, -INFINITY};
    float lrun[4] = {0.f, 0.f, 0.f, 0.f};

    // staging registers (next round's K/V)
    uint4 rK[2][2], rV[2][2];
    // prologue: load round kb=0
    #pragma unroll
    for (int s = 0; s < 2; ++s)
        #pragma unroll
        for (int cc = 0; cc < 2; ++cc) {
            const int ch = tid + cc * 256;
            const int row = ch >> 3, u = ch & 7;
            uint4 kvv = make_uint4(0u, 0u, 0u, 0u);
            uint4 vvv = make_uint4(0u, 0u, 0u, 0u);
            if (u < 7)
                kvv = *reinterpret_cast<const uint4*>(
                    Kg + (size_t)(s * 64 + row) * ND + u * 8);
            if (row < ND)
                vvv = *reinterpret_cast<const uint4*>(
                    Vg + (size_t)row * NT + s * 64 + u * 8);
            rK[s][cc] = kvv; rV[s][cc] = vvv;
        }

    for (int kb = 0; kb <= qb; kb += 128) {
        // ---- write staged regs to LDS (swizzled slots) ----
        #pragma unroll
        for (int s = 0; s < 2; ++s)
            #pragma unroll
            for (int cc = 0; cc < 2; ++cc) {
                const int ch = tid + cc * 256;
                const int row = ch >> 3, u = ch & 7;
                const int sl = (row * 8 + (u ^ (row & 7))) * 8;
                *reinterpret_cast<uint4*>(&Ks[s][sl])  = rK[s][cc];
                *reinterpret_cast<uint4*>(&Vts[s][sl]) = rV[s][cc];
            }
        __syncthreads();

        // ---- prefetch next round into regs (hidden under compute) ----
        if (kb + 128 <= qb) {
            #pragma unroll
            for (int s = 0; s < 2; ++s)
                #pragma unroll
                for (int cc = 0; cc < 2; ++cc) {
                    const int ch = tid + cc * 256;
                    const int row = ch >> 3, u = ch & 7;
                    uint4 kvv = make_uint4(0u, 0u, 0u, 0u);
                    uint4 vvv = make_uint4(0u, 0u, 0u, 0u);
                    if (u < 7)
                        kvv = *reinterpret_cast<const uint4*>(
                            Kg + (size_t)(kb + 128 + s * 64 + row) * ND + u * 8);
                    if (row < ND)
                        vvv = *reinterpret_cast<const uint4*>(
                            Vg + (size_t)row * NT + kb + 128 + s * 64 + u * 8);
                    rK[s][cc] = kvv; rV[s][cc] = vvv;
                }
        }

        // ---- QK^T both subtiles: S[16 q][128 key] per wave (16 MFMAs) ----
        f32x4 sc[2][4];
        __builtin_amdgcn_s_setprio(1);
        #pragma unroll
        for (int s = 0; s < 2; ++s)
            #pragma unroll
            for (int n = 0; n < 4; ++n) {
                const int krow = n * 16 + lr;
                const bf16x8 kf0 = *reinterpret_cast<const bf16x8*>(
                    &Ks[s][(krow * 8 + ((0 + lg) ^ (krow & 7))) * 8]);
                const bf16x8 kf1 = *reinterpret_cast<const bf16x8*>(
                    &Ks[s][(krow * 8 + ((4 + lg) ^ (krow & 7))) * 8]);
                f32x4 a = fzero;
                a = __builtin_amdgcn_mfma_f32_16x16x32_bf16(qf[0], kf0, a, 0, 0, 0);
                a = __builtin_amdgcn_mfma_f32_16x16x32_bf16(qf[1], kf1, a, 0, 0, 0);
                sc[s][n] = a;
            }
        __builtin_amdgcn_s_setprio(0);

        // causal mask (scores stay UNSCALED; scale folded into exp via fma)
        #pragma unroll
        for (int s = 0; s < 2; ++s) {
            const int kbs = kb + s * 64;
            if (kbs + 63 > qb) {
                #pragma unroll
                for (int n = 0; n < 4; ++n) {
                    const int key = kbs + n * 16 + lr;
                    #pragma unroll
                    for (int r = 0; r < 4; ++r) {
                        const int qr = qb + w * 16 + lg * 4 + r;
                        if (key > qr) sc[s][n][r] = -1e30f;
                    }
                }
            }
        }

        // ---- merged online softmax over 128 keys (deferred scale) ----
        float alpha[4];
        #pragma unroll
        for (int r = 0; r < 4; ++r) {
            float tmax = fmaxf(
                fmaxf(fmaxf(sc[0][0][r], sc[0][1][r]), fmaxf(sc[0][2][r], sc[0][3][r])),
                fmaxf(fmaxf(sc[1][0][r], sc[1][1][r]), fmaxf(sc[1][2][r], sc[1][3][r])));
            tmax = fmaxf(tmax, __shfl_xor(tmax, 1));
            tmax = fmaxf(tmax, __shfl_xor(tmax, 2));
            tmax = fmaxf(tmax, __shfl_xor(tmax, 4));
            tmax = fmaxf(tmax, __shfl_xor(tmax, 8));
            const float mnew = fmaxf(mrun[r], tmax);
            const float c = SCALE * mnew;
            alpha[r] = __expf(fmaf(SCALE, mrun[r], -c));  // first round: exp(-inf)=0
            mrun[r]  = mnew;
            float tsum = 0.f;
            #pragma unroll
            for (int s = 0; s < 2; ++s)
                #pragma unroll
                for (int n = 0; n < 4; ++n) {
                    const float p = __expf(fmaf(SCALE, sc[s][n][r], -c));
                    sc[s][n][r] = p;
                    tsum += p;
                }
            tsum += __shfl_xor(tsum, 1);
            tsum += __shfl_xor(tsum, 2);
            tsum += __shfl_xor(tsum, 4);
            tsum += __shfl_xor(tsum, 8);
            lrun[r] = lrun[r] * alpha[r] + tsum;
        }
        #pragma unroll
        for (int n = 0; n < 4; ++n)
            #pragma unroll
            for (int r = 0; r < 4; ++r) o[n][r] *= alpha[r];

        // ---- PV per subtile (P pack -> wave-local LDS -> A-frags) ----
        unsigned short* Pw = Pl[w];
        #pragma unroll
        for (int s = 0; s < 2; ++s) {
            #pragma unroll
            for (int n = 0; n < 4; ++n) {
                const int u = n * 2 + (lr >> 3);
                #pragma unroll
                for (int r = 0; r < 4; ++r) {
                    const int prow = lg * 4 + r;
                    Pw[(prow * 8 + (u ^ (prow & 7))) * 8 + (lr & 7)] =
                        f2bf(sc[s][n][r]);
                }
            }
            const bf16x8 pf0 = *reinterpret_cast<const bf16x8*>(
                &Pw[(lr * 8 + ((0 + lg) ^ (lr & 7))) * 8]);
            const bf16x8 pf1 = *reinterpret_cast<const bf16x8*>(
                &Pw[(lr * 8 + ((4 + lg) ^ (lr & 7))) * 8]);
            __builtin_amdgcn_s_setprio(1);
            #pragma unroll
            for (int n = 0; n < 4; ++n) {
                const int vrow = n * 16 + lr;
                const bf16x8 vf0 = *reinterpret_cast<const bf16x8*>(
                    &Vts[s][(vrow * 8 + ((0 + lg) ^ (vrow & 7))) * 8]);
                const bf16x8 vf1 = *reinterpret_cast<const bf16x8*>(
                    &Vts[s][(vrow * 8 + ((4 + lg) ^ (vrow & 7))) * 8]);
                o[n] = __builtin_amdgcn_mfma_f32_16x16x32_bf16(pf0, vf0, o[n], 0, 0, 0);
                o[n] = __builtin_amdgcn_mfma_f32_16x16x32_bf16(pf1, vf1, o[n], 0, 0, 0);
            }
            __builtin_amdgcn_s_setprio(0);
        }
        __syncthreads();   // protect LDS before next round's writes
    }

    // ---- epilogue: normalize, emit bf16 hi/lo att [B][T][C] ----
    #pragma unroll
    for (int r = 0; r < 4; ++r) {
        const float inv = 1.0f / lrun[r];
        const int trow = qb + w * 16 + lg * 4 + r;
        const size_t rbase = ((size_t)b * NT + trow) * NC + h * ND;
        #pragma unroll
        for (int n = 0; n < 4; ++n) {
            const int c = n * 16 + lr;
            if (c < ND) {
                const float val = o[n][r] * inv;
                const unsigned short hh = f2bf(val);
                att_h[rbase + c] = hh;
                att_l[rbase + c] = f2bf(val - bf2f(hh));
            }
        }
    }
}

// ---------------------------------------------------------------------------
extern "C" void kernel_launch(void* const* d_in, const int* in_sizes, int n_in,
                              void* d_out, int out_size, void* d_ws, size_t ws_size,
                              hipStream_t stream)
{
    const float* x  = (const float*)d_in[0];
    const float* Wq = (const float*)d_in[1];
    const float* Wk = (const float*)d_in[2];
    const float* Wv = (const float*)d_in[3];
    const float* Wp = (const float*)d_in[4];
    const float* bp = (const float*)d_in[5];
    float* out = (float*)d_out;

    const size_t BTC = (size_t)NM * NC;        // 3,670,016
    const size_t WSZ = (size_t)NC * NC;        // 200,704
    unsigned short* p = (unsigned short*)d_ws;
    unsigned short* xh  = p;            p += BTC;
    unsigned short* xl  = p;            p += BTC;
    unsigned short* wth = p;            p += 4 * WSZ;   // q,k,v,p transposed hi
    unsigned short* wtl = p;            p += 4 * WSZ;
    unsigned short* qw  = p;            p += BTC;
    unsigned short* kw  = p;            p += BTC;
    unsigned short* vtw = p;            p += BTC;
    unsigned short* ath = p;            p += BTC;
    unsigned short* atl = p;            p += BTC;

    dim3 blk(256);
    conv_x_kernel<<<dim3((unsigned)(BTC / 1024)), blk, 0, stream>>>(x, xh, xl);
    conv_wt_kernel<<<dim3(NC / 32, NC / 32, 4), blk, 0, stream>>>(
        Wq, Wk, Wv, Wp, wth, wtl);
    qkv_mfma_kernel<<<dim3(NC / 64, NM / 128, 3), blk, 0, stream>>>(
        xh, xl, wth, wtl, qw, kw, vtw);
    // Attention: grid (bh INNER, qtile OUTER) for CU load balance
    attn_mfma_kernel<<<dim3(NB * NH, NT / 64), blk, 0, stream>>>(
        qw, kw, vtw, ath, atl);
    proj_mfma_kernel<<<dim3(NC / 64, NM / 128, 1), blk, 0, stream>>>(
        ath, atl, wth + 3 * WSZ, wtl + 3 * WSZ, bp, out);
}

// Round 13
// 215.791 us; speedup vs baseline: 4.9417x; 1.0509x over previous
//
#include <hip/hip_runtime.h>
#include <math.h>

// Problem constants (B=4, T=2048, C=448, H=8, d=56)
#define NB 4
#define NT 2048
#define NC 448
#define NH 8
#define ND 56
#define NM (NB * NT)          // 8192 rows
#define SCALE 0.04724555912615705f  // 1/sqrt(448)

typedef __attribute__((ext_vector_type(8))) short bf16x8;
typedef __attribute__((ext_vector_type(4))) float f32x4;

__device__ __forceinline__ unsigned short f2bf(float f) {
    unsigned u = __float_as_uint(f);
    u += 0x7fffu + ((u >> 16) & 1u);       // round-to-nearest-even
    return (unsigned short)(u >> 16);
}
__device__ __forceinline__ float bf2f(unsigned short h) {
    return __uint_as_float(((unsigned)h) << 16);
}

// async global->LDS, 16B per lane; lds dest must be wave-uniform base
__device__ __forceinline__ void gl_lds16(const unsigned short* g, unsigned short* l) {
    __builtin_amdgcn_global_load_lds(
        (const __attribute__((address_space(1))) unsigned int*)g,
        (__attribute__((address_space(3))) unsigned int*)l,
        16, 0, 0);
}

// swizzled 16B-slot index inside a [rows][32-bf16] tile (4 slots/row)
__device__ __forceinline__ int sw_slot(int row, int u) {
    return row * 4 + (u ^ ((row >> 1) & 3));
}

// ---------------------------------------------------------------------------
// Kernel 0a: x (fp32 [8192][448]) -> xh, xl (bf16 hi/lo, same layout)
// ---------------------------------------------------------------------------
__global__ __launch_bounds__(256) void conv_x_kernel(
    const float* __restrict__ x, unsigned short* __restrict__ xh,
    unsigned short* __restrict__ xl)
{
    const size_t i4 = ((size_t)blockIdx.x * 256 + threadIdx.x) * 4;
    const float4 v = *reinterpret_cast<const float4*>(x + i4);
    ushort4 h, l;
    h.x = f2bf(v.x); l.x = f2bf(v.x - bf2f(h.x));
    h.y = f2bf(v.y); l.y = f2bf(v.y - bf2f(h.y));
    h.z = f2bf(v.z); l.z = f2bf(v.z - bf2f(h.z));
    h.w = f2bf(v.w); l.w = f2bf(v.w - bf2f(h.w));
    *reinterpret_cast<ushort4*>(xh + i4) = h;
    *reinterpret_cast<ushort4*>(xl + i4) = l;
}

// ---------------------------------------------------------------------------
// Kernel 0b: W (fp32 [K=448][N=448]) -> Wt hi/lo (bf16 [N][K], transposed).
// z selects {Wq, Wk, Wv, Wp}. 32x32 LDS tile transpose, block 256 (32x8).
// ---------------------------------------------------------------------------
__global__ __launch_bounds__(256) void conv_wt_kernel(
    const float* __restrict__ Wq, const float* __restrict__ Wk,
    const float* __restrict__ Wv, const float* __restrict__ Wp,
    unsigned short* __restrict__ wth, unsigned short* __restrict__ wtl)
{
    const int z = blockIdx.z;
    const float* __restrict__ W =
        (z == 0) ? Wq : ((z == 1) ? Wk : ((z == 2) ? Wv : Wp));
    unsigned short* __restrict__ oh = wth + (size_t)z * NC * NC;
    unsigned short* __restrict__ ol = wtl + (size_t)z * NC * NC;

    __shared__ float t[32][33];
    const int tx = threadIdx.x & 31;
    const int ty = threadIdx.x >> 5;         // 0..7
    const int x0 = blockIdx.x * 32;          // n base (src cols)
    const int y0 = blockIdx.y * 32;          // k base (src rows)

    #pragma unroll
    for (int i = 0; i < 4; ++i)
        t[ty + i * 8][tx] = W[(size_t)(y0 + ty + i * 8) * NC + x0 + tx];
    __syncthreads();
    #pragma unroll
    for (int i = 0; i < 4; ++i) {
        const int n = x0 + ty + i * 8;
        const int k = y0 + tx;
        const float v = t[tx][ty + i * 8];
        const unsigned short h = f2bf(v);
        oh[(size_t)n * NC + k] = h;
        ol[(size_t)n * NC + k] = f2bf(v - bf2f(h));
    }
}

// ---------------------------------------------------------------------------
// Kernel 1: QKV projection via split-bf16 MFMA, ALL THREE weights per block.
// A-tile (x hi/lo) staged ONCE per k-step and reused for Wq/Wk/Wv (3x fewer
// A fetches from HBM than the z-grid version). acc[3][4][2], LDS 40KB.
// ---------------------------------------------------------------------------
__global__ __launch_bounds__(256) void qkv_mfma_kernel(
    const unsigned short* __restrict__ xh, const unsigned short* __restrict__ xl,
    const unsigned short* __restrict__ wth, const unsigned short* __restrict__ wtl,
    unsigned short* __restrict__ qo, unsigned short* __restrict__ ko,
    unsigned short* __restrict__ vo)
{
    __shared__ unsigned short Ah[128 * 32], Al[128 * 32];      // 8 KiB each
    __shared__ unsigned short Bh[3][64 * 32], Bl[3][64 * 32];  // 4 KiB each
    const int tid = threadIdx.x;
    const int l  = tid & 63, w = tid >> 6;
    const int lg = l >> 4,  lr = l & 15;
    const int wr = w >> 1,  wc = w & 1;
    const int rowBase = blockIdx.y * 128;
    const int colBase = blockIdx.x * 64;

    f32x4 acc[3][4][2];
    #pragma unroll
    for (int z = 0; z < 3; ++z)
        #pragma unroll
        for (int m = 0; m < 4; ++m)
            #pragma unroll
            for (int n = 0; n < 2; ++n) acc[z][m][n] = (f32x4){0.f, 0.f, 0.f, 0.f};

    for (int k0 = 0; k0 < NC; k0 += 32) {
        __syncthreads();
        // ---- stage A tile once (2 slots/thread, hi+lo) ----
        #pragma unroll
        for (int i = 0; i < 2; ++i) {
            const int p   = w * 64 + 256 * i + l;
            const int row = p >> 2, ps = p & 3;
            const int u   = ps ^ ((row >> 1) & 3);
            const size_t src = (size_t)(rowBase + row) * NC + k0 + u * 8;
            const int dst = (w * 64 + 256 * i) * 8;     // ush elems, wave-uniform
            gl_lds16(xh + src, Ah + dst);
            gl_lds16(xl + src, Al + dst);
        }
        // ---- stage B tiles for all 3 weights (1 slot/thread each) ----
        {
            const int p   = tid;
            const int row = p >> 2, ps = p & 3;
            const int u   = ps ^ ((row >> 1) & 3);
            const size_t off = (size_t)(colBase + row) * NC + k0 + u * 8;
            #pragma unroll
            for (int z = 0; z < 3; ++z) {
                const size_t src = (size_t)z * NC * NC + off;
                gl_lds16(wth + src, &Bh[z][w * 512]);
                gl_lds16(wtl + src, &Bl[z][w * 512]);
            }
        }
        __syncthreads();

        bf16x8 a_h[4], a_l[4];
        #pragma unroll
        for (int m = 0; m < 4; ++m) {
            const int row = wr * 64 + m * 16 + lr;
            const int s   = sw_slot(row, lg) * 8;
            a_h[m] = *reinterpret_cast<const bf16x8*>(Ah + s);
            a_l[m] = *reinterpret_cast<const bf16x8*>(Al + s);
        }
        #pragma unroll
        for (int z = 0; z < 3; ++z) {
            bf16x8 b_h[2], b_l[2];
            #pragma unroll
            for (int n = 0; n < 2; ++n) {
                const int row = wc * 32 + n * 16 + lr;
                const int s   = sw_slot(row, lg) * 8;
                b_h[n] = *reinterpret_cast<const bf16x8*>(&Bh[z][s]);
                b_l[n] = *reinterpret_cast<const bf16x8*>(&Bl[z][s]);
            }
            #pragma unroll
            for (int m = 0; m < 4; ++m)
                #pragma unroll
                for (int n = 0; n < 2; ++n) {
                    acc[z][m][n] = __builtin_amdgcn_mfma_f32_16x16x32_bf16(
                        a_h[m], b_h[n], acc[z][m][n], 0, 0, 0);
                    acc[z][m][n] = __builtin_amdgcn_mfma_f32_16x16x32_bf16(
                        a_h[m], b_l[n], acc[z][m][n], 0, 0, 0);
                    acc[z][m][n] = __builtin_amdgcn_mfma_f32_16x16x32_bf16(
                        a_l[m], b_h[n], acc[z][m][n], 0, 0, 0);
                }
        }
    }

    // Epilogue: D row=(lg*4+reg), col=lr within each 16x16 frag (m89 layout).
    const int mW = rowBase + wr * 64;
    const int nW = colBase + wc * 32;
    #pragma unroll
    for (int z = 0; z < 3; ++z) {
        if (z < 2) {
            unsigned short* __restrict__ dst = (z == 0) ? qo : ko;
            #pragma unroll
            for (int m = 0; m < 4; ++m) {
                #pragma unroll
                for (int n = 0; n < 2; ++n) {
                    const int gcol = nW + n * 16 + lr;
                    const int h = gcol / ND, c = gcol - h * ND;
                    #pragma unroll
                    for (int r = 0; r < 4; ++r) {
                        const int grow = mW + m * 16 + lg * 4 + r;
                        const int b = grow >> 11, t = grow & (NT - 1);
                        dst[((size_t)(b * NH + h) * NT + t) * ND + c] =
                            f2bf(acc[z][m][n][r]);
                    }
                }
            }
        } else {
            // v transposed: vo[bh][c][t0..t0+3] -- t0 multiple of 4, 8B-aligned
            #pragma unroll
            for (int m = 0; m < 4; ++m) {
                const int grow0 = mW + m * 16 + lg * 4;
                const int b = grow0 >> 11, t0 = grow0 & (NT - 1);
                #pragma unroll
                for (int n = 0; n < 2; ++n) {
                    const int gcol = nW + n * 16 + lr;
                    const int h = gcol / ND, c = gcol - h * ND;
                    ushort4 pk;
                    pk.x = f2bf(acc[z][m][n][0]); pk.y = f2bf(acc[z][m][n][1]);
                    pk.z = f2bf(acc[z][m][n][2]); pk.w = f2bf(acc[z][m][n][3]);
                    *reinterpret_cast<ushort4*>(
                        vo + ((size_t)(b * NH + h) * ND + c) * NT + t0) = pk;
                }
            }
        }
    }
}

// ---------------------------------------------------------------------------
// Kernel 3: output projection via split-bf16 MFMA. out = att @ Wp + bp (fp32).
// ---------------------------------------------------------------------------
__global__ __launch_bounds__(256) void proj_mfma_kernel(
    const unsigned short* __restrict__ ah_g, const unsigned short* __restrict__ al_g,
    const unsigned short* __restrict__ bth, const unsigned short* __restrict__ btl,
    const float* __restrict__ bias, float* __restrict__ out)
{
    __shared__ unsigned short Ah[128 * 32], Al[128 * 32];
    __shared__ unsigned short Bh[64 * 32],  Bl[64 * 32];
    const int tid = threadIdx.x;
    const int l  = tid & 63, w = tid >> 6;
    const int lg = l >> 4,  lr = l & 15;
    const int wr = w >> 1,  wc = w & 1;
    const int rowBase = blockIdx.y * 128;
    const int colBase = blockIdx.x * 64;

    f32x4 acc[4][2];
    #pragma unroll
    for (int m = 0; m < 4; ++m)
        #pragma unroll
        for (int n = 0; n < 2; ++n) acc[m][n] = (f32x4){0.f, 0.f, 0.f, 0.f};

    for (int k0 = 0; k0 < NC; k0 += 32) {
        __syncthreads();
        #pragma unroll
        for (int i = 0; i < 2; ++i) {
            const int p   = w * 64 + 256 * i + l;
            const int row = p >> 2, ps = p & 3;
            const int u   = ps ^ ((row >> 1) & 3);
            const size_t src = (size_t)(rowBase + row) * NC + k0 + u * 8;
            const int dst = (w * 64 + 256 * i) * 8;
            gl_lds16(ah_g + src, Ah + dst);
            gl_lds16(al_g + src, Al + dst);
        }
        {
            const int p   = w * 64 + l;
            const int row = p >> 2, ps = p & 3;
            const int u   = ps ^ ((row >> 1) & 3);
            const size_t src = (size_t)(colBase + row) * NC + k0 + u * 8;
            gl_lds16(bth + src, Bh + w * 512);
            gl_lds16(btl + src, Bl + w * 512);
        }
        __syncthreads();

        bf16x8 a_h[4], a_l[4], b_h[2], b_l[2];
        #pragma unroll
        for (int m = 0; m < 4; ++m) {
            const int row = wr * 64 + m * 16 + lr;
            const int s   = sw_slot(row, lg) * 8;
            a_h[m] = *reinterpret_cast<const bf16x8*>(Ah + s);
            a_l[m] = *reinterpret_cast<const bf16x8*>(Al + s);
        }
        #pragma unroll
        for (int n = 0; n < 2; ++n) {
            const int row = wc * 32 + n * 16 + lr;
            const int s   = sw_slot(row, lg) * 8;
            b_h[n] = *reinterpret_cast<const bf16x8*>(Bh + s);
            b_l[n] = *reinterpret_cast<const bf16x8*>(Bl + s);
        }
        #pragma unroll
        for (int m = 0; m < 4; ++m)
            #pragma unroll
            for (int n = 0; n < 2; ++n) {
                acc[m][n] = __builtin_amdgcn_mfma_f32_16x16x32_bf16(
                    a_h[m], b_h[n], acc[m][n], 0, 0, 0);
                acc[m][n] = __builtin_amdgcn_mfma_f32_16x16x32_bf16(
                    a_h[m], b_l[n], acc[m][n], 0, 0, 0);
                acc[m][n] = __builtin_amdgcn_mfma_f32_16x16x32_bf16(
                    a_l[m], b_h[n], acc[m][n], 0, 0, 0);
            }
    }

    const int mW = rowBase + wr * 64;
    const int nW = colBase + wc * 32;
    #pragma unroll
    for (int n = 0; n < 2; ++n) {
        const int gcol = nW + n * 16 + lr;
        const float bv = bias[gcol];
        #pragma unroll
        for (int m = 0; m < 4; ++m) {
            #pragma unroll
            for (int r = 0; r < 4; ++r) {
                const int grow = mW + m * 16 + lg * 4 + r;
                out[(size_t)grow * NC + gcol] = acc[m][n][r] + bv;
            }
        }
    }
}

// ---------------------------------------------------------------------------
// Kernel 2: causal flash attention, bf16 MFMA, fp32 merged online softmax.
// Grid (bh, qtile) -- bh INNER so co-scheduled blocks span different qtiles
// (load balance) and same-XCD blocks share bh%8 K/V in L2. Deferred-scale
// softmax via fma. KVBLK=128, register-prefetch pipeline, setprio on MFMA.
// ---------------------------------------------------------------------------
__global__ __launch_bounds__(256) void attn_mfma_kernel(
    const unsigned short* __restrict__ q, const unsigned short* __restrict__ k,
    const unsigned short* __restrict__ vt,
    unsigned short* __restrict__ att_h, unsigned short* __restrict__ att_l)
{
    const int bh = blockIdx.x;                          // 0..31
    const int qb = (gridDim.y - 1 - blockIdx.y) * 64;   // big tiles first
    const int b  = bh >> 3;
    const int h  = bh & 7;

    const int tid = threadIdx.x;
    const int w   = tid >> 6;
    const int l   = tid & 63;
    const int lg  = l >> 4;
    const int lr  = l & 15;

    __shared__ unsigned short Ks [2][64 * 64];   // 16 KiB (key x d)
    __shared__ unsigned short Vts[2][64 * 64];   // 16 KiB (d x key)
    __shared__ unsigned short Pl[4][16 * 64];    // 8 KiB per-wave P

    const unsigned short* __restrict__ Qg = q  + (size_t)bh * NT * ND;
    const unsigned short* __restrict__ Kg = k  + (size_t)bh * NT * ND;
    const unsigned short* __restrict__ Vg = vt + (size_t)bh * ND * NT;

    // Q fragments (A-operand), held across the whole kv loop.
    bf16x8 qf[2];
    {
        const int row = qb + w * 16 + lr;
        #pragma unroll
        for (int hh = 0; hh < 2; ++hh) {
            const int d0 = hh * 32 + lg * 8;
            bf16x8 tmp = {0, 0, 0, 0, 0, 0, 0, 0};
            if (d0 < ND)
                tmp = *reinterpret_cast<const bf16x8*>(Qg + (size_t)row * ND + d0);
            qf[hh] = tmp;
        }
    }

    const f32x4 fzero = {0.f, 0.f, 0.f, 0.f};
    f32x4 o[4];
    #pragma unroll
    for (int n = 0; n < 4; ++n) o[n] = fzero;
    float mrun[4] = {-INFINITY, -INFINITY, -INFINITY, -INFINITY};
    float lrun[4] = {0.f, 0.f, 0.f, 0.f};

    // staging registers (next round's K/V)
    uint4 rK[2][2], rV[2][2];
    // prologue: load round kb=0
    #pragma unroll
    for (int s = 0; s < 2; ++s)
        #pragma unroll
        for (int cc = 0; cc < 2; ++cc) {
            const int ch = tid + cc * 256;
            const int row = ch >> 3, u = ch & 7;
            uint4 kvv = make_uint4(0u, 0u, 0u, 0u);
            uint4 vvv = make_uint4(0u, 0u, 0u, 0u);
            if (u < 7)
                kvv = *reinterpret_cast<const uint4*>(
                    Kg + (size_t)(s * 64 + row) * ND + u * 8);
            if (row < ND)
                vvv = *reinterpret_cast<const uint4*>(
                    Vg + (size_t)row * NT + s * 64 + u * 8);
            rK[s][cc] = kvv; rV[s][cc] = vvv;
        }

    for (int kb = 0; kb <= qb; kb += 128) {
        // ---- write staged regs to LDS (swizzled slots) ----
        #pragma unroll
        for (int s = 0; s < 2; ++s)
            #pragma unroll
            for (int cc = 0; cc < 2; ++cc) {
                const int ch = tid + cc * 256;
                const int row = ch >> 3, u = ch & 7;
                const int sl = (row * 8 + (u ^ (row & 7))) * 8;
                *reinterpret_cast<uint4*>(&Ks[s][sl])  = rK[s][cc];
                *reinterpret_cast<uint4*>(&Vts[s][sl]) = rV[s][cc];
            }
        __syncthreads();

        // ---- prefetch next round into regs (hidden under compute) ----
        if (kb + 128 <= qb) {
            #pragma unroll
            for (int s = 0; s < 2; ++s)
                #pragma unroll
                for (int cc = 0; cc < 2; ++cc) {
                    const int ch = tid + cc * 256;
                    const int row = ch >> 3, u = ch & 7;
                    uint4 kvv = make_uint4(0u, 0u, 0u, 0u);
                    uint4 vvv = make_uint4(0u, 0u, 0u, 0u);
                    if (u < 7)
                        kvv = *reinterpret_cast<const uint4*>(
                            Kg + (size_t)(kb + 128 + s * 64 + row) * ND + u * 8);
                    if (row < ND)
                        vvv = *reinterpret_cast<const uint4*>(
                            Vg + (size_t)row * NT + kb + 128 + s * 64 + u * 8);
                    rK[s][cc] = kvv; rV[s][cc] = vvv;
                }
        }

        // ---- QK^T both subtiles: S[16 q][128 key] per wave (16 MFMAs) ----
        f32x4 sc[2][4];
        __builtin_amdgcn_s_setprio(1);
        #pragma unroll
        for (int s = 0; s < 2; ++s)
            #pragma unroll
            for (int n = 0; n < 4; ++n) {
                const int krow = n * 16 + lr;
                const bf16x8 kf0 = *reinterpret_cast<const bf16x8*>(
                    &Ks[s][(krow * 8 + ((0 + lg) ^ (krow & 7))) * 8]);
                const bf16x8 kf1 = *reinterpret_cast<const bf16x8*>(
                    &Ks[s][(krow * 8 + ((4 + lg) ^ (krow & 7))) * 8]);
                f32x4 a = fzero;
                a = __builtin_amdgcn_mfma_f32_16x16x32_bf16(qf[0], kf0, a, 0, 0, 0);
                a = __builtin_amdgcn_mfma_f32_16x16x32_bf16(qf[1], kf1, a, 0, 0, 0);
                sc[s][n] = a;
            }
        __builtin_amdgcn_s_setprio(0);

        // causal mask (scores stay UNSCALED; scale folded into exp via fma)
        #pragma unroll
        for (int s = 0; s < 2; ++s) {
            const int kbs = kb + s * 64;
            if (kbs + 63 > qb) {
                #pragma unroll
                for (int n = 0; n < 4; ++n) {
                    const int key = kbs + n * 16 + lr;
                    #pragma unroll
                    for (int r = 0; r < 4; ++r) {
                        const int qr = qb + w * 16 + lg * 4 + r;
                        if (key > qr) sc[s][n][r] = -1e30f;
                    }
                }
            }
        }

        // ---- merged online softmax over 128 keys (deferred scale) ----
        float alpha[4];
        #pragma unroll
        for (int r = 0; r < 4; ++r) {
            float tmax = fmaxf(
                fmaxf(fmaxf(sc[0][0][r], sc[0][1][r]), fmaxf(sc[0][2][r], sc[0][3][r])),
                fmaxf(fmaxf(sc[1][0][r], sc[1][1][r]), fmaxf(sc[1][2][r], sc[1][3][r])));
            tmax = fmaxf(tmax, __shfl_xor(tmax, 1));
            tmax = fmaxf(tmax, __shfl_xor(tmax, 2));
            tmax = fmaxf(tmax, __shfl_xor(tmax, 4));
            tmax = fmaxf(tmax, __shfl_xor(tmax, 8));
            const float mnew = fmaxf(mrun[r], tmax);
            const float c = SCALE * mnew;
            alpha[r] = __expf(fmaf(SCALE, mrun[r], -c));  // first round: exp(-inf)=0
            mrun[r]  = mnew;
            float tsum = 0.f;
            #pragma unroll
            for (int s = 0; s < 2; ++s)
                #pragma unroll
                for (int n = 0; n < 4; ++n) {
                    const float p = __expf(fmaf(SCALE, sc[s][n][r], -c));
                    sc[s][n][r] = p;
                    tsum += p;
                }
            tsum += __shfl_xor(tsum, 1);
            tsum += __shfl_xor(tsum, 2);
            tsum += __shfl_xor(tsum, 4);
            tsum += __shfl_xor(tsum, 8);
            lrun[r] = lrun[r] * alpha[r] + tsum;
        }
        #pragma unroll
        for (int n = 0; n < 4; ++n)
            #pragma unroll
            for (int r = 0; r < 4; ++r) o[n][r] *= alpha[r];

        // ---- PV per subtile (P pack -> wave-local LDS -> A-frags) ----
        unsigned short* Pw = Pl[w];
        #pragma unroll
        for (int s = 0; s < 2; ++s) {
            #pragma unroll
            for (int n = 0; n < 4; ++n) {
                const int u = n * 2 + (lr >> 3);
                #pragma unroll
                for (int r = 0; r < 4; ++r) {
                    const int prow = lg * 4 + r;
                    Pw[(prow * 8 + (u ^ (prow & 7))) * 8 + (lr & 7)] =
                        f2bf(sc[s][n][r]);
                }
            }
            const bf16x8 pf0 = *reinterpret_cast<const bf16x8*>(
                &Pw[(lr * 8 + ((0 + lg) ^ (lr & 7))) * 8]);
            const bf16x8 pf1 = *reinterpret_cast<const bf16x8*>(
                &Pw[(lr * 8 + ((4 + lg) ^ (lr & 7))) * 8]);
            __builtin_amdgcn_s_setprio(1);
            #pragma unroll
            for (int n = 0; n < 4; ++n) {
                const int vrow = n * 16 + lr;
                const bf16x8 vf0 = *reinterpret_cast<const bf16x8*>(
                    &Vts[s][(vrow * 8 + ((0 + lg) ^ (vrow & 7))) * 8]);
                const bf16x8 vf1 = *reinterpret_cast<const bf16x8*>(
                    &Vts[s][(vrow * 8 + ((4 + lg) ^ (vrow & 7))) * 8]);
                o[n] = __builtin_amdgcn_mfma_f32_16x16x32_bf16(pf0, vf0, o[n], 0, 0, 0);
                o[n] = __builtin_amdgcn_mfma_f32_16x16x32_bf16(pf1, vf1, o[n], 0, 0, 0);
            }
            __builtin_amdgcn_s_setprio(0);
        }
        __syncthreads();   // protect LDS before next round's writes
    }

    // ---- epilogue: normalize, emit bf16 hi/lo att [B][T][C] ----
    #pragma unroll
    for (int r = 0; r < 4; ++r) {
        const float inv = 1.0f / lrun[r];
        const int trow = qb + w * 16 + lg * 4 + r;
        const size_t rbase = ((size_t)b * NT + trow) * NC + h * ND;
        #pragma unroll
        for (int n = 0; n < 4; ++n) {
            const int c = n * 16 + lr;
            if (c < ND) {
                const float val = o[n][r] * inv;
                const unsigned short hh = f2bf(val);
                att_h[rbase + c] = hh;
                att_l[rbase + c] = f2bf(val - bf2f(hh));
            }
        }
    }
}

// ---------------------------------------------------------------------------
extern "C" void kernel_launch(void* const* d_in, const int* in_sizes, int n_in,
                              void* d_out, int out_size, void* d_ws, size_t ws_size,
                              hipStream_t stream)
{
    const float* x  = (const float*)d_in[0];
    const float* Wq = (const float*)d_in[1];
    const float* Wk = (const float*)d_in[2];
    const float* Wv = (const float*)d_in[3];
    const float* Wp = (const float*)d_in[4];
    const float* bp = (const float*)d_in[5];
    float* out = (float*)d_out;

    const size_t BTC = (size_t)NM * NC;        // 3,670,016
    const size_t WSZ = (size_t)NC * NC;        // 200,704
    unsigned short* p = (unsigned short*)d_ws;
    unsigned short* xh  = p;            p += BTC;
    unsigned short* xl  = p;            p += BTC;
    unsigned short* wth = p;            p += 4 * WSZ;   // q,k,v,p transposed hi
    unsigned short* wtl = p;            p += 4 * WSZ;
    unsigned short* qw  = p;            p += BTC;
    unsigned short* kw  = p;            p += BTC;
    unsigned short* vtw = p;            p += BTC;
    unsigned short* ath = p;            p += BTC;
    unsigned short* atl = p;            p += BTC;

    dim3 blk(256);
    conv_x_kernel<<<dim3((unsigned)(BTC / 1024)), blk, 0, stream>>>(x, xh, xl);
    conv_wt_kernel<<<dim3(NC / 32, NC / 32, 4), blk, 0, stream>>>(
        Wq, Wk, Wv, Wp, wth, wtl);
    // QKV: one block computes q,k,v for its tile (A staged once, 3 B's)
    qkv_mfma_kernel<<<dim3(NC / 64, NM / 128), blk, 0, stream>>>(
        xh, xl, wth, wtl, qw, kw, vtw);
    // Attention: grid (bh INNER, qtile OUTER) for CU load balance
    attn_mfma_kernel<<<dim3(NB * NH, NT / 64), blk, 0, stream>>>(
        qw, kw, vtw, ath, atl);
    proj_mfma_kernel<<<dim3(NC / 64, NM / 128, 1), blk, 0, stream>>>(
        ath, atl, wth + 3 * WSZ, wtl + 3 * WSZ, bp, out);
}

// Round 14
// 202.118 us; speedup vs baseline: 5.2760x; 1.0676x over previous
//
#include <hip/hip_runtime.h>
#include <math.h>

// Problem constants (B=4, T=2048, C=448, H=8, d=56)
#define NB 4
#define NT 2048
#define NC 448
#define NH 8
#define ND 56
#define NM (NB * NT)          // 8192 rows
#define SCALE 0.04724555912615705f  // 1/sqrt(448)

typedef __attribute__((ext_vector_type(8))) short bf16x8;
typedef __attribute__((ext_vector_type(4))) float f32x4;

__device__ __forceinline__ unsigned short f2bf(float f) {
    unsigned u = __float_as_uint(f);
    u += 0x7fffu + ((u >> 16) & 1u);       // round-to-nearest-even
    return (unsigned short)(u >> 16);
}
__device__ __forceinline__ float bf2f(unsigned short h) {
    return __uint_as_float(((unsigned)h) << 16);
}

// async global->LDS, 16B per lane; lds dest must be wave-uniform base
__device__ __forceinline__ void gl_lds16(const unsigned short* g, unsigned short* l) {
    __builtin_amdgcn_global_load_lds(
        (const __attribute__((address_space(1))) unsigned int*)g,
        (__attribute__((address_space(3))) unsigned int*)l,
        16, 0, 0);
}

// swizzled 16B-slot index inside a [rows][32-bf16] tile (4 slots/row)
__device__ __forceinline__ int sw_slot(int row, int u) {
    return row * 4 + (u ^ ((row >> 1) & 3));
}

// ---------------------------------------------------------------------------
// Kernel 0a: x (fp32 [8192][448]) -> xh, xl (bf16 hi/lo, same layout)
// ---------------------------------------------------------------------------
__global__ __launch_bounds__(256) void conv_x_kernel(
    const float* __restrict__ x, unsigned short* __restrict__ xh,
    unsigned short* __restrict__ xl)
{
    const size_t i4 = ((size_t)blockIdx.x * 256 + threadIdx.x) * 4;
    const float4 v = *reinterpret_cast<const float4*>(x + i4);
    ushort4 h, l;
    h.x = f2bf(v.x); l.x = f2bf(v.x - bf2f(h.x));
    h.y = f2bf(v.y); l.y = f2bf(v.y - bf2f(h.y));
    h.z = f2bf(v.z); l.z = f2bf(v.z - bf2f(h.z));
    h.w = f2bf(v.w); l.w = f2bf(v.w - bf2f(h.w));
    *reinterpret_cast<ushort4*>(xh + i4) = h;
    *reinterpret_cast<ushort4*>(xl + i4) = l;
}

// ---------------------------------------------------------------------------
// Kernel 0b: W (fp32 [K=448][N=448]) -> Wt hi/lo (bf16 [N][K], transposed).
// ---------------------------------------------------------------------------
__global__ __launch_bounds__(256) void conv_wt_kernel(
    const float* __restrict__ Wq, const float* __restrict__ Wk,
    const float* __restrict__ Wv, const float* __restrict__ Wp,
    unsigned short* __restrict__ wth, unsigned short* __restrict__ wtl)
{
    const int z = blockIdx.z;
    const float* __restrict__ W =
        (z == 0) ? Wq : ((z == 1) ? Wk : ((z == 2) ? Wv : Wp));
    unsigned short* __restrict__ oh = wth + (size_t)z * NC * NC;
    unsigned short* __restrict__ ol = wtl + (size_t)z * NC * NC;

    __shared__ float t[32][33];
    const int tx = threadIdx.x & 31;
    const int ty = threadIdx.x >> 5;         // 0..7
    const int x0 = blockIdx.x * 32;          // n base (src cols)
    const int y0 = blockIdx.y * 32;          // k base (src rows)

    #pragma unroll
    for (int i = 0; i < 4; ++i)
        t[ty + i * 8][tx] = W[(size_t)(y0 + ty + i * 8) * NC + x0 + tx];
    __syncthreads();
    #pragma unroll
    for (int i = 0; i < 4; ++i) {
        const int n = x0 + ty + i * 8;
        const int k = y0 + tx;
        const float v = t[tx][ty + i * 8];
        const unsigned short h = f2bf(v);
        oh[(size_t)n * NC + k] = h;
        ol[(size_t)n * NC + k] = f2bf(v - bf2f(h));
    }
}

// ---------------------------------------------------------------------------
// Kernel 1: QKV projection via split-bf16 MFMA, ALL THREE weights per block.
// ---------------------------------------------------------------------------
__global__ __launch_bounds__(256) void qkv_mfma_kernel(
    const unsigned short* __restrict__ xh, const unsigned short* __restrict__ xl,
    const unsigned short* __restrict__ wth, const unsigned short* __restrict__ wtl,
    unsigned short* __restrict__ qo, unsigned short* __restrict__ ko,
    unsigned short* __restrict__ vo)
{
    __shared__ unsigned short Ah[128 * 32], Al[128 * 32];      // 8 KiB each
    __shared__ unsigned short Bh[3][64 * 32], Bl[3][64 * 32];  // 4 KiB each
    const int tid = threadIdx.x;
    const int l  = tid & 63, w = tid >> 6;
    const int lg = l >> 4,  lr = l & 15;
    const int wr = w >> 1,  wc = w & 1;
    const int rowBase = blockIdx.y * 128;
    const int colBase = blockIdx.x * 64;

    f32x4 acc[3][4][2];
    #pragma unroll
    for (int z = 0; z < 3; ++z)
        #pragma unroll
        for (int m = 0; m < 4; ++m)
            #pragma unroll
            for (int n = 0; n < 2; ++n) acc[z][m][n] = (f32x4){0.f, 0.f, 0.f, 0.f};

    for (int k0 = 0; k0 < NC; k0 += 32) {
        __syncthreads();
        #pragma unroll
        for (int i = 0; i < 2; ++i) {
            const int p   = w * 64 + 256 * i + l;
            const int row = p >> 2, ps = p & 3;
            const int u   = ps ^ ((row >> 1) & 3);
            const size_t src = (size_t)(rowBase + row) * NC + k0 + u * 8;
            const int dst = (w * 64 + 256 * i) * 8;     // ush elems, wave-uniform
            gl_lds16(xh + src, Ah + dst);
            gl_lds16(xl + src, Al + dst);
        }
        {
            const int p   = tid;
            const int row = p >> 2, ps = p & 3;
            const int u   = ps ^ ((row >> 1) & 3);
            const size_t off = (size_t)(colBase + row) * NC + k0 + u * 8;
            #pragma unroll
            for (int z = 0; z < 3; ++z) {
                const size_t src = (size_t)z * NC * NC + off;
                gl_lds16(wth + src, &Bh[z][w * 512]);
                gl_lds16(wtl + src, &Bl[z][w * 512]);
            }
        }
        __syncthreads();

        bf16x8 a_h[4], a_l[4];
        #pragma unroll
        for (int m = 0; m < 4; ++m) {
            const int row = wr * 64 + m * 16 + lr;
            const int s   = sw_slot(row, lg) * 8;
            a_h[m] = *reinterpret_cast<const bf16x8*>(Ah + s);
            a_l[m] = *reinterpret_cast<const bf16x8*>(Al + s);
        }
        #pragma unroll
        for (int z = 0; z < 3; ++z) {
            bf16x8 b_h[2], b_l[2];
            #pragma unroll
            for (int n = 0; n < 2; ++n) {
                const int row = wc * 32 + n * 16 + lr;
                const int s   = sw_slot(row, lg) * 8;
                b_h[n] = *reinterpret_cast<const bf16x8*>(&Bh[z][s]);
                b_l[n] = *reinterpret_cast<const bf16x8*>(&Bl[z][s]);
            }
            #pragma unroll
            for (int m = 0; m < 4; ++m)
                #pragma unroll
                for (int n = 0; n < 2; ++n) {
                    acc[z][m][n] = __builtin_amdgcn_mfma_f32_16x16x32_bf16(
                        a_h[m], b_h[n], acc[z][m][n], 0, 0, 0);
                    acc[z][m][n] = __builtin_amdgcn_mfma_f32_16x16x32_bf16(
                        a_h[m], b_l[n], acc[z][m][n], 0, 0, 0);
                    acc[z][m][n] = __builtin_amdgcn_mfma_f32_16x16x32_bf16(
                        a_l[m], b_h[n], acc[z][m][n], 0, 0, 0);
                }
        }
    }

    const int mW = rowBase + wr * 64;
    const int nW = colBase + wc * 32;
    #pragma unroll
    for (int z = 0; z < 3; ++z) {
        if (z < 2) {
            unsigned short* __restrict__ dst = (z == 0) ? qo : ko;
            #pragma unroll
            for (int m = 0; m < 4; ++m) {
                #pragma unroll
                for (int n = 0; n < 2; ++n) {
                    const int gcol = nW + n * 16 + lr;
                    const int h = gcol / ND, c = gcol - h * ND;
                    #pragma unroll
                    for (int r = 0; r < 4; ++r) {
                        const int grow = mW + m * 16 + lg * 4 + r;
                        const int b = grow >> 11, t = grow & (NT - 1);
                        dst[((size_t)(b * NH + h) * NT + t) * ND + c] =
                            f2bf(acc[z][m][n][r]);
                    }
                }
            }
        } else {
            #pragma unroll
            for (int m = 0; m < 4; ++m) {
                const int grow0 = mW + m * 16 + lg * 4;
                const int b = grow0 >> 11, t0 = grow0 & (NT - 1);
                #pragma unroll
                for (int n = 0; n < 2; ++n) {
                    const int gcol = nW + n * 16 + lr;
                    const int h = gcol / ND, c = gcol - h * ND;
                    ushort4 pk;
                    pk.x = f2bf(acc[z][m][n][0]); pk.y = f2bf(acc[z][m][n][1]);
                    pk.z = f2bf(acc[z][m][n][2]); pk.w = f2bf(acc[z][m][n][3]);
                    *reinterpret_cast<ushort4*>(
                        vo + ((size_t)(b * NH + h) * ND + c) * NT + t0) = pk;
                }
            }
        }
    }
}

// ---------------------------------------------------------------------------
// Kernel 3: output projection via split-bf16 MFMA. out = att @ Wp + bp (fp32).
// ---------------------------------------------------------------------------
__global__ __launch_bounds__(256) void proj_mfma_kernel(
    const unsigned short* __restrict__ ah_g, const unsigned short* __restrict__ al_g,
    const unsigned short* __restrict__ bth, const unsigned short* __restrict__ btl,
    const float* __restrict__ bias, float* __restrict__ out)
{
    __shared__ unsigned short Ah[128 * 32], Al[128 * 32];
    __shared__ unsigned short Bh[64 * 32],  Bl[64 * 32];
    const int tid = threadIdx.x;
    const int l  = tid & 63, w = tid >> 6;
    const int lg = l >> 4,  lr = l & 15;
    const int wr = w >> 1,  wc = w & 1;
    const int rowBase = blockIdx.y * 128;
    const int colBase = blockIdx.x * 64;

    f32x4 acc[4][2];
    #pragma unroll
    for (int m = 0; m < 4; ++m)
        #pragma unroll
        for (int n = 0; n < 2; ++n) acc[m][n] = (f32x4){0.f, 0.f, 0.f, 0.f};

    for (int k0 = 0; k0 < NC; k0 += 32) {
        __syncthreads();
        #pragma unroll
        for (int i = 0; i < 2; ++i) {
            const int p   = w * 64 + 256 * i + l;
            const int row = p >> 2, ps = p & 3;
            const int u   = ps ^ ((row >> 1) & 3);
            const size_t src = (size_t)(rowBase + row) * NC + k0 + u * 8;
            const int dst = (w * 64 + 256 * i) * 8;
            gl_lds16(ah_g + src, Ah + dst);
            gl_lds16(al_g + src, Al + dst);
        }
        {
            const int p   = w * 64 + l;
            const int row = p >> 2, ps = p & 3;
            const int u   = ps ^ ((row >> 1) & 3);
            const size_t src = (size_t)(colBase + row) * NC + k0 + u * 8;
            gl_lds16(bth + src, Bh + w * 512);
            gl_lds16(btl + src, Bl + w * 512);
        }
        __syncthreads();

        bf16x8 a_h[4], a_l[4], b_h[2], b_l[2];
        #pragma unroll
        for (int m = 0; m < 4; ++m) {
            const int row = wr * 64 + m * 16 + lr;
            const int s   = sw_slot(row, lg) * 8;
            a_h[m] = *reinterpret_cast<const bf16x8*>(Ah + s);
            a_l[m] = *reinterpret_cast<const bf16x8*>(Al + s);
        }
        #pragma unroll
        for (int n = 0; n < 2; ++n) {
            const int row = wc * 32 + n * 16 + lr;
            const int s   = sw_slot(row, lg) * 8;
            b_h[n] = *reinterpret_cast<const bf16x8*>(Bh + s);
            b_l[n] = *reinterpret_cast<const bf16x8*>(Bl + s);
        }
        #pragma unroll
        for (int m = 0; m < 4; ++m)
            #pragma unroll
            for (int n = 0; n < 2; ++n) {
                acc[m][n] = __builtin_amdgcn_mfma_f32_16x16x32_bf16(
                    a_h[m], b_h[n], acc[m][n], 0, 0, 0);
                acc[m][n] = __builtin_amdgcn_mfma_f32_16x16x32_bf16(
                    a_h[m], b_l[n], acc[m][n], 0, 0, 0);
                acc[m][n] = __builtin_amdgcn_mfma_f32_16x16x32_bf16(
                    a_l[m], b_h[n], acc[m][n], 0, 0, 0);
            }
    }

    const int mW = rowBase + wr * 64;
    const int nW = colBase + wc * 32;
    #pragma unroll
    for (int n = 0; n < 2; ++n) {
        const int gcol = nW + n * 16 + lr;
        const float bv = bias[gcol];
        #pragma unroll
        for (int m = 0; m < 4; ++m) {
            #pragma unroll
            for (int r = 0; r < 4; ++r) {
                const int grow = mW + m * 16 + lg * 4 + r;
                out[(size_t)grow * NC + gcol] = acc[m][n][r] + bv;
            }
        }
    }
}

// ---------------------------------------------------------------------------
// Kernel 2: causal flash attention, SWAPPED-operand QK^T (S^T = mfma(K,Q)):
// each lane owns the full softmax row for q = lr (within-lane 32 values +
// shfl_xor 16,32). P packed via v_cvt_pk_bf16_f32 into compact u32 LDS
// (chunk-XOR swizzle), PV = mfma(Vt, P^T) -> O^T[d][q]. Fragment loads are
// identical to the HW-validated layout (A/B lane maps are symmetric).
// ---------------------------------------------------------------------------
__global__ __launch_bounds__(256) void attn_mfma_kernel(
    const unsigned short* __restrict__ q, const unsigned short* __restrict__ k,
    const unsigned short* __restrict__ vt,
    unsigned short* __restrict__ att_h, unsigned short* __restrict__ att_l)
{
    const int bh = blockIdx.x;                          // 0..31
    const int qb = (gridDim.y - 1 - blockIdx.y) * 64;   // big tiles first
    const int b  = bh >> 3;
    const int h  = bh & 7;

    const int tid = threadIdx.x;
    const int w   = tid >> 6;
    const int l   = tid & 63;
    const int lg  = l >> 4;
    const int lr  = l & 15;

    __shared__ unsigned short Ks [2][64 * 64];   // 16 KiB (key x d)
    __shared__ unsigned short Vts[2][64 * 64];   // 16 KiB (d x key)
    __shared__ unsigned int   Pt[4][16 * 32];    // 8 KiB per-wave packed P^T

    const unsigned short* __restrict__ Qg = q  + (size_t)bh * NT * ND;
    const unsigned short* __restrict__ Kg = k  + (size_t)bh * NT * ND;
    const unsigned short* __restrict__ Vg = vt + (size_t)bh * ND * NT;

    // Q fragments (B-operand now; same lane layout/load as before).
    bf16x8 qf[2];
    {
        const int row = qb + w * 16 + lr;
        #pragma unroll
        for (int hh = 0; hh < 2; ++hh) {
            const int d0 = hh * 32 + lg * 8;
            bf16x8 tmp = {0, 0, 0, 0, 0, 0, 0, 0};
            if (d0 < ND)
                tmp = *reinterpret_cast<const bf16x8*>(Qg + (size_t)row * ND + d0);
            qf[hh] = tmp;
        }
    }

    const f32x4 fzero = {0.f, 0.f, 0.f, 0.f};
    f32x4 o[4];                      // O^T: d = n*16 + lg*4 + r, q = lr
    #pragma unroll
    for (int n = 0; n < 4; ++n) o[n] = fzero;
    float mrun = -INFINITY;
    float lrun = 0.f;
    const int qr = qb + w * 16 + lr;  // this lane's q row

    // staging registers (next round's K/V)
    uint4 rK[2][2], rV[2][2];
    #pragma unroll
    for (int s = 0; s < 2; ++s)
        #pragma unroll
        for (int cc = 0; cc < 2; ++cc) {
            const int ch = tid + cc * 256;
            const int row = ch >> 3, u = ch & 7;
            uint4 kvv = make_uint4(0u, 0u, 0u, 0u);
            uint4 vvv = make_uint4(0u, 0u, 0u, 0u);
            if (u < 7)
                kvv = *reinterpret_cast<const uint4*>(
                    Kg + (size_t)(s * 64 + row) * ND + u * 8);
            if (row < ND)
                vvv = *reinterpret_cast<const uint4*>(
                    Vg + (size_t)row * NT + s * 64 + u * 8);
            rK[s][cc] = kvv; rV[s][cc] = vvv;
        }

    for (int kb = 0; kb <= qb; kb += 128) {
        // ---- write staged regs to LDS (swizzled slots) ----
        #pragma unroll
        for (int s = 0; s < 2; ++s)
            #pragma unroll
            for (int cc = 0; cc < 2; ++cc) {
                const int ch = tid + cc * 256;
                const int row = ch >> 3, u = ch & 7;
                const int sl = (row * 8 + (u ^ (row & 7))) * 8;
                *reinterpret_cast<uint4*>(&Ks[s][sl])  = rK[s][cc];
                *reinterpret_cast<uint4*>(&Vts[s][sl]) = rV[s][cc];
            }
        __syncthreads();

        // ---- prefetch next round into regs (hidden under compute) ----
        if (kb + 128 <= qb) {
            #pragma unroll
            for (int s = 0; s < 2; ++s)
                #pragma unroll
                for (int cc = 0; cc < 2; ++cc) {
                    const int ch = tid + cc * 256;
                    const int row = ch >> 3, u = ch & 7;
                    uint4 kvv = make_uint4(0u, 0u, 0u, 0u);
                    uint4 vvv = make_uint4(0u, 0u, 0u, 0u);
                    if (u < 7)
                        kvv = *reinterpret_cast<const uint4*>(
                            Kg + (size_t)(kb + 128 + s * 64 + row) * ND + u * 8);
                    if (row < ND)
                        vvv = *reinterpret_cast<const uint4*>(
                            Vg + (size_t)row * NT + kb + 128 + s * 64 + u * 8);
                    rK[s][cc] = kvv; rV[s][cc] = vvv;
                }
        }

        // ---- QK^T swapped: sc[s][n] = S^T[key=n*16+lg*4+r][q=lr] ----
        f32x4 sc[2][4];
        __builtin_amdgcn_s_setprio(1);
        #pragma unroll
        for (int s = 0; s < 2; ++s)
            #pragma unroll
            for (int n = 0; n < 4; ++n) {
                const int krow = n * 16 + lr;
                const bf16x8 kf0 = *reinterpret_cast<const bf16x8*>(
                    &Ks[s][(krow * 8 + ((0 + lg) ^ (krow & 7))) * 8]);
                const bf16x8 kf1 = *reinterpret_cast<const bf16x8*>(
                    &Ks[s][(krow * 8 + ((4 + lg) ^ (krow & 7))) * 8]);
                f32x4 a = fzero;
                a = __builtin_amdgcn_mfma_f32_16x16x32_bf16(kf0, qf[0], a, 0, 0, 0);
                a = __builtin_amdgcn_mfma_f32_16x16x32_bf16(kf1, qf[1], a, 0, 0, 0);
                sc[s][n] = a;
            }
        __builtin_amdgcn_s_setprio(0);

        // causal mask (unscaled scores; scale folded into exp via fma)
        #pragma unroll
        for (int s = 0; s < 2; ++s) {
            const int kbs = kb + s * 64;
            if (kbs + 63 > qb) {     // block-uniform guard
                #pragma unroll
                for (int n = 0; n < 4; ++n)
                    #pragma unroll
                    for (int r = 0; r < 4; ++r) {
                        const int key = kbs + n * 16 + lg * 4 + r;
                        if (key > qr) sc[s][n][r] = -1e30f;
                    }
            }
        }

        // ---- merged online softmax: lane-local row (32 vals) + 2 shfl ----
        float tm[8];
        #pragma unroll
        for (int s = 0; s < 2; ++s)
            #pragma unroll
            for (int n = 0; n < 4; ++n)
                tm[s * 4 + n] = fmaxf(fmaxf(sc[s][n][0], sc[s][n][1]),
                                      fmaxf(sc[s][n][2], sc[s][n][3]));
        float tmax = fmaxf(fmaxf(fmaxf(tm[0], tm[1]), fmaxf(tm[2], tm[3])),
                           fmaxf(fmaxf(tm[4], tm[5]), fmaxf(tm[6], tm[7])));
        tmax = fmaxf(tmax, __shfl_xor(tmax, 16));
        tmax = fmaxf(tmax, __shfl_xor(tmax, 32));
        const float mnew = fmaxf(mrun, tmax);
        const float c = SCALE * mnew;
        const float alpha = __expf(fmaf(SCALE, mrun, -c));  // 1st round: exp(-inf)=0
        mrun = mnew;
        float tsum = 0.f;
        #pragma unroll
        for (int s = 0; s < 2; ++s)
            #pragma unroll
            for (int n = 0; n < 4; ++n)
                #pragma unroll
                for (int r = 0; r < 4; ++r) {
                    const float p = __expf(fmaf(SCALE, sc[s][n][r], -c));
                    sc[s][n][r] = p;
                    tsum += p;
                }
        tsum += __shfl_xor(tsum, 16);
        tsum += __shfl_xor(tsum, 32);
        lrun = lrun * alpha + tsum;
        #pragma unroll
        for (int n = 0; n < 4; ++n)
            #pragma unroll
            for (int r = 0; r < 4; ++r) o[n][r] *= alpha;

        // ---- PV per subtile: pack P^T (cvt_pk) -> LDS -> B-frags ----
        unsigned int* Pw = Pt[w];
        #pragma unroll
        for (int s = 0; s < 2; ++s) {
            #pragma unroll
            for (int np = 0; np < 4; ++np)
                #pragma unroll
                for (int hh = 0; hh < 2; ++hh) {
                    unsigned int pk;
                    asm("v_cvt_pk_bf16_f32 %0, %1, %2"
                        : "=v"(pk)
                        : "v"(sc[s][np][2 * hh]), "v"(sc[s][np][2 * hh + 1]));
                    const int word = np * 8 + lg * 2 + hh;          // key pair idx
                    const int phys = ((word >> 2) ^ (lr & 7)) * 4 + (word & 3);
                    Pw[lr * 32 + phys] = pk;
                }
            __builtin_amdgcn_s_setprio(1);
            #pragma unroll
            for (int ks = 0; ks < 2; ++ks) {
                const bf16x8 pb = *reinterpret_cast<const bf16x8*>(
                    &Pw[lr * 32 + (((ks * 4 + lg) ^ (lr & 7)) * 4)]);
                #pragma unroll
                for (int n = 0; n < 4; ++n) {
                    const int vrow = n * 16 + lr;
                    const bf16x8 vf = *reinterpret_cast<const bf16x8*>(
                        &Vts[s][(vrow * 8 + ((ks * 4 + lg) ^ (vrow & 7))) * 8]);
                    o[n] = __builtin_amdgcn_mfma_f32_16x16x32_bf16(
                        vf, pb, o[n], 0, 0, 0);
                }
            }
            __builtin_amdgcn_s_setprio(0);
        }
        __syncthreads();   // protect LDS before next round's writes
    }

    // ---- epilogue: normalize, emit bf16 hi/lo att [B][T][C] (vector4) ----
    const float inv = 1.0f / lrun;
    const size_t rbase = ((size_t)b * NT + qr) * NC + h * ND;
    #pragma unroll
    for (int n = 0; n < 4; ++n) {
        const int d0 = n * 16 + lg * 4;
        if (d0 < ND) {
            float v0 = o[n][0] * inv, v1 = o[n][1] * inv;
            float v2 = o[n][2] * inv, v3 = o[n][3] * inv;
            ushort4 ph, pl;
            ph.x = f2bf(v0); pl.x = f2bf(v0 - bf2f(ph.x));
            ph.y = f2bf(v1); pl.y = f2bf(v1 - bf2f(ph.y));
            ph.z = f2bf(v2); pl.z = f2bf(v2 - bf2f(ph.z));
            ph.w = f2bf(v3); pl.w = f2bf(v3 - bf2f(ph.w));
            *reinterpret_cast<ushort4*>(att_h + rbase + d0) = ph;
            *reinterpret_cast<ushort4*>(att_l + rbase + d0) = pl;
        }
    }
}

// ---------------------------------------------------------------------------
extern "C" void kernel_launch(void* const* d_in, const int* in_sizes, int n_in,
                              void* d_out, int out_size, void* d_ws, size_t ws_size,
                              hipStream_t stream)
{
    const float* x  = (const float*)d_in[0];
    const float* Wq = (const float*)d_in[1];
    const float* Wk = (const float*)d_in[2];
    const float* Wv = (const float*)d_in[3];
    const float* Wp = (const float*)d_in[4];
    const float* bp = (const float*)d_in[5];
    float* out = (float*)d_out;

    const size_t BTC = (size_t)NM * NC;        // 3,670,016
    const size_t WSZ = (size_t)NC * NC;        // 200,704
    unsigned short* p = (unsigned short*)d_ws;
    unsigned short* xh  = p;            p += BTC;
    unsigned short* xl  = p;            p += BTC;
    unsigned short* wth = p;            p += 4 * WSZ;   // q,k,v,p transposed hi
    unsigned short* wtl = p;            p += 4 * WSZ;
    unsigned short* qw  = p;            p += BTC;
    unsigned short* kw  = p;            p += BTC;
    unsigned short* vtw = p;            p += BTC;
    unsigned short* ath = p;            p += BTC;
    unsigned short* atl = p;            p += BTC;

    dim3 blk(256);
    conv_x_kernel<<<dim3((unsigned)(BTC / 1024)), blk, 0, stream>>>(x, xh, xl);
    conv_wt_kernel<<<dim3(NC / 32, NC / 32, 4), blk, 0, stream>>>(
        Wq, Wk, Wv, Wp, wth, wtl);
    // QKV: one block computes q,k,v for its tile (A staged once, 3 B's)
    qkv_mfma_kernel<<<dim3(NC / 64, NM / 128), blk, 0, stream>>>(
        xh, xl, wth, wtl, qw, kw, vtw);
    // Attention: grid (bh INNER, qtile OUTER) for CU load balance
    attn_mfma_kernel<<<dim3(NB * NH, NT / 64), blk, 0, stream>>>(
        qw, kw, vtw, ath, atl);
    proj_mfma_kernel<<<dim3(NC / 64, NM / 128, 1), blk, 0, stream>>>(
        ath, atl, wth + 3 * WSZ, wtl + 3 * WSZ, bp, out);
}